// Round 1
// baseline (4446.291 us; speedup 1.0000x reference)
//
#include <hip/hip_runtime.h>
#include <math.h>

#define NN 10000
#define NE 160000
#define SDIM 256
#define VDIM 32
#define L2DIM 16
#define TDIM 128
#define FEAT 528      // S + 3V + 3V + 5*L2
#define WOUT 400      // S + 4V + L2
#define ESD 700       // 16+16+20+8+S+S+TDIM
#define ADA 592       // 2S+2V+L2
#define DEG_INV 0.25f

#define ET 16         // edges per block
#define ESP 708       // padded edge_scalars stride (708%32=4 -> <=2-way LDS conflicts)
#define WLP 408       // padded w stride

// ---------------------------------------------------------------- sv = s @ sv_W
__global__ __launch_bounds__(256) void sv_kernel(const float* __restrict__ hcur,
                                                 const float* __restrict__ svW,
                                                 float* __restrict__ sv) {
    int i = blockIdx.x * 256 + threadIdx.x;
    if (i >= NN * VDIM) return;
    int n = i >> 5, v = i & 31;
    const float* hs = hcur + (size_t)n * FEAT;
    float acc = 0.f;
    for (int k = 0; k < SDIM; ++k) acc = fmaf(hs[k], svW[k * VDIM + v], acc);
    sv[i] = acc;
}

// ---------------------------------------------------------------- edge kernel
__global__ __launch_bounds__(256) void edge_kernel(
    const float* __restrict__ hcur, const float* __restrict__ t_emb,
    const float* __restrict__ coords, const float* __restrict__ erd,
    const float* __restrict__ sv,
    const float* __restrict__ W, const float* __restrict__ bvec,
    const int* __restrict__ eidx,
    const int* __restrict__ etype, const int* __restrict__ ebt,
    const int* __restrict__ ebc, const int* __restrict__ ebr,
    const int* __restrict__ ebs,
    const float* __restrict__ etype_emb, const float* __restrict__ btype_emb,
    const float* __restrict__ bconj_emb, const float* __restrict__ bring_emb,
    const float* __restrict__ bstereo_emb,
    const float* __restrict__ refW, const float* __restrict__ refb,
    float* __restrict__ agg_s, float* __restrict__ agg_v1o,
    float* __restrict__ agg_v1e, float* __restrict__ agg_l2)
{
    __shared__ float smem[ET * ESP];          // edge_scalars, later reused for w
    __shared__ int   srcl[ET], dstl[ET];
    __shared__ int   itype[ET], ibt[ET], ibc[ET], ibr[ET], ibs[ET];
    __shared__ float distl[ET], erdl[ET], y1l[ET][3];

    const int tid = threadIdx.x;
    const int e0  = blockIdx.x * ET;

    if (tid < ET) {
        int ge = e0 + tid;
        int s = eidx[ge], d = eidx[NE + ge];
        srcl[tid] = s; dstl[tid] = d;
        itype[tid] = etype[ge]; ibt[tid] = ebt[ge]; ibc[tid] = ebc[ge];
        ibr[tid] = ebr[ge]; ibs[tid] = ebs[ge];
        float dx = coords[d*3+0] - coords[s*3+0];
        float dy = coords[d*3+1] - coords[s*3+1];
        float dz = coords[d*3+2] - coords[s*3+2];
        float dist = sqrtf(dx*dx + dy*dy + dz*dz);
        distl[tid] = dist;
        float inv = 1.f / (dist + 1e-8f);
        y1l[tid][0] = dx * inv; y1l[tid][1] = dy * inv; y1l[tid][2] = dz * inv;
        erdl[tid] = erd[ge];
    }
    __syncthreads();

    // ---- build edge_scalars in LDS
    for (int e = 0; e < ET; ++e) {
        const int src = srcl[e], dst = dstl[e];
        const float* hs = hcur + (size_t)src * FEAT;
        const float* hd = hcur + (size_t)dst * FEAT;
        const float* td = t_emb + (size_t)dst * TDIM;
        const float de = distl[e];
        for (int k = tid; k < ESD; k += 256) {
            float v;
            if (k < 16) { float x = (de - (float)k * (10.f/15.f)) * 1.6f; v = expf(-x*x); }
            else if (k < 32) v = etype_emb[itype[e]*16 + (k-16)];
            else if (k < 40) v = btype_emb[ibt[e]*8 + (k-32)];
            else if (k < 44) v = bconj_emb[ibc[e]*4 + (k-40)];
            else if (k < 48) v = bring_emb[ibr[e]*4 + (k-44)];
            else if (k < 52) v = bstereo_emb[ibs[e]*4 + (k-48)];
            else if (k < 60) {
                int j = k - 52;
                float dd = de - erdl[e];
                float hr = erdl[e] > 0.f ? 1.f : 0.f;
                v = fabsf(dd)*refW[j] + dd*refW[8+j] + hr*refW[16+j] + refb[j];
            }
            else if (k < 60 + SDIM)     v = hs[k - 60];
            else if (k < 60 + 2*SDIM)   v = hd[k - 316];
            else                        v = td[k - 572];
            smem[e * ESP + k] = v;
        }
    }
    __syncthreads();

    // ---- GEMM: each thread owns output column c1 (and c2 if tid<144) for all 16 edges
    const int c1 = tid;
    const bool has2 = tid < (WOUT - SDIM);          // 144
    const int c2 = has2 ? (SDIM + tid) : (WOUT - 1);
    float acc1[ET], acc2[ET];
    #pragma unroll
    for (int e = 0; e < ET; ++e) { acc1[e] = 0.f; acc2[e] = 0.f; }

    for (int k = 0; k < ESD; k += 2) {
        float w1a = W[(size_t)k * WOUT + c1];
        float w1b = W[(size_t)(k+1) * WOUT + c1];
        float w2a = W[(size_t)k * WOUT + c2];
        float w2b = W[(size_t)(k+1) * WOUT + c2];
        #pragma unroll
        for (int e = 0; e < ET; ++e) {
            float a0 = smem[e * ESP + k];
            float a1 = smem[e * ESP + k + 1];
            acc1[e] = fmaf(a0, w1a, acc1[e]);
            acc1[e] = fmaf(a1, w1b, acc1[e]);
            acc2[e] = fmaf(a0, w2a, acc2[e]);
            acc2[e] = fmaf(a1, w2b, acc2[e]);
        }
    }
    __syncthreads();   // done reading edge_scalars; smem becomes w

    float* wl = smem;  // [ET][WLP]
    {
        float b1 = bvec[c1];
        float b2 = bvec[c2];
        #pragma unroll
        for (int e = 0; e < ET; ++e) {
            wl[e * WLP + c1] = acc1[e] + b1;
            if (has2) wl[e * WLP + c2] = acc2[e] + b2;
        }
    }
    __syncthreads();

    // ---- scalar messages: m_s = w_s * s[src], scatter to dst
    for (int e = 0; e < ET; ++e) {
        const int src = srcl[e], dst = dstl[e];
        float ms = wl[e * WLP + c1] * hcur[(size_t)src * FEAT + c1];
        atomicAdd(&agg_s[(size_t)dst * SDIM + c1], ms);
    }

    // ---- vector messages: 16 edges x 32 channels = 512 items, 2 rounds
    for (int r = 0; r < 2; ++r) {
        int it = r * 256 + tid;
        int e = it >> 5, c = it & 31;
        const int src = srcl[e], dst = dstl[e];
        float wv1 = wl[e * WLP + SDIM + c];
        float wsv = wl[e * WLP + SDIM + VDIM + c];
        float wv2 = wl[e * WLP + SDIM + 2*VDIM + c];
        float wcx = wl[e * WLP + SDIM + 3*VDIM + c];
        float svv = sv[(size_t)src * VDIM + c];
        const float* vo = hcur + (size_t)src * FEAT + SDIM + c*3;
        const float* ve = hcur + (size_t)src * FEAT + SDIM + 3*VDIM + c*3;
        float y0 = y1l[e][0], y1 = y1l[e][1], y2 = y1l[e][2];
        float a0 = vo[0], a1 = vo[1], a2 = vo[2];
        float cx0 = a1*y2 - a2*y1;
        float cx1 = a2*y0 - a0*y2;
        float cx2 = a0*y1 - a1*y0;
        float t = wsv * svv;
        float* po = &agg_v1o[(size_t)dst * 3*VDIM + c*3];
        float* pe = &agg_v1e[(size_t)dst * 3*VDIM + c*3];
        atomicAdd(po + 0, wv1*a0 + t*y0);
        atomicAdd(po + 1, wv1*a1 + t*y1);
        atomicAdd(po + 2, wv1*a2 + t*y2);
        atomicAdd(pe + 0, wv2*ve[0] + wcx*cx0);
        atomicAdd(pe + 1, wv2*ve[1] + wcx*cx1);
        atomicAdd(pe + 2, wv2*ve[2] + wcx*cx2);
    }

    // ---- l2 messages: 16 edges x 16 channels = 256 items
    {
        int e = tid >> 4, c = tid & 15;
        const int src = srcl[e], dst = dstl[e];
        float w2 = wl[e * WLP + SDIM + 4*VDIM + c];
        const float* q = hcur + (size_t)src * FEAT + SDIM + 6*VDIM + c*5;
        float* pq = &agg_l2[(size_t)dst * 5*L2DIM + c*5];
        #pragma unroll
        for (int i = 0; i < 5; ++i) atomicAdd(pq + i, w2 * q[i]);
    }
}

// ---------------------------------------------------------------- node kernel
__device__ __forceinline__ float block_reduce_sum(float v, float* red, int tid) {
    #pragma unroll
    for (int off = 32; off > 0; off >>= 1) v += __shfl_down(v, off, 64);
    if ((tid & 63) == 0) red[tid >> 6] = v;
    __syncthreads();
    float s = red[0] + red[1] + red[2] + red[3];
    __syncthreads();
    return s;
}

__global__ __launch_bounds__(256) void node_kernel(
    const float* __restrict__ hcur, const float* __restrict__ t_emb,
    const float* __restrict__ agg_s, const float* __restrict__ agg_v1o,
    const float* __restrict__ agg_v1e, const float* __restrict__ agg_l2,
    const float* __restrict__ proj_s, const float* __restrict__ proj_v1,
    const float* __restrict__ proj_v2, const float* __restrict__ proj_l2,
    const float* __restrict__ adaW, const float* __restrict__ adab,
    float* __restrict__ hnext)
{
    const int n = blockIdx.x;
    const int tid = threadIdx.x;
    __shared__ float a_s[SDIM];
    __shared__ float te[TDIM];
    __shared__ float ada[ADA];
    __shared__ float snew[SDIM];
    __shared__ float av[272];    // 96 v1o + 96 v1e + 80 l2 (scaled aggs)
    __shared__ float vbuf[272];  // residual-added values before norm
    __shared__ float red[8];

    a_s[tid] = agg_s[(size_t)n * SDIM + tid] * DEG_INV;
    if (tid < TDIM) te[tid] = t_emb[(size_t)n * TDIM + tid];
    for (int i = tid; i < 272; i += 256) {
        float val;
        if (i < 96)        val = agg_v1o[(size_t)n * 96 + i];
        else if (i < 192)  val = agg_v1e[(size_t)n * 96 + (i - 96)];
        else               val = agg_l2[(size_t)n * 80 + (i - 192)];
        av[i] = val * DEG_INV;
    }
    __syncthreads();

    // ada = t_emb @ ada_W + ada_b
    for (int r = 0; r < 3; ++r) {
        int col = r * 256 + tid;
        if (col < ADA) {
            float acc = adab[col];
            for (int k = 0; k < TDIM; ++k) acc = fmaf(te[k], adaW[(size_t)k * ADA + col], acc);
            ada[col] = acc;
        }
    }

    // u_s = silu(agg_s @ proj_s); s_new = s + u_s
    float acc = 0.f;
    for (int k = 0; k < SDIM; ++k) acc = fmaf(a_s[k], proj_s[(size_t)k * SDIM + tid], acc);
    float us = acc / (1.f + expf(-acc));
    float sn = hcur[(size_t)n * FEAT + tid] + us;
    snew[tid] = sn;

    // vector/l2 proj + residual
    if (tid < 96) {
        int d = tid / 3, i = tid - d * 3;
        float a = 0.f;
        #pragma unroll
        for (int c = 0; c < VDIM; ++c) a = fmaf(av[c*3 + i], proj_v1[c * VDIM + d], a);
        vbuf[tid] = hcur[(size_t)n * FEAT + SDIM + tid] + a;
    } else if (tid < 192) {
        int t2 = tid - 96;
        int d = t2 / 3, i = t2 - d * 3;
        float a = 0.f;
        #pragma unroll
        for (int c = 0; c < VDIM; ++c) a = fmaf(av[96 + c*3 + i], proj_v2[c * VDIM + d], a);
        vbuf[tid] = hcur[(size_t)n * FEAT + SDIM + 3*VDIM + t2] + a;
    }
    if (tid < 80) {
        int d = tid / 5, i = tid - d * 5;
        float a = 0.f;
        #pragma unroll
        for (int c = 0; c < L2DIM; ++c) a = fmaf(av[192 + c*5 + i], proj_l2[c * L2DIM + d], a);
        vbuf[192 + tid] = hcur[(size_t)n * FEAT + SDIM + 6*VDIM + tid] + a;
    }
    __syncthreads();

    // LayerNorm on s
    float ssum = block_reduce_sum(sn, red, tid);
    float ssq  = block_reduce_sum(sn * sn, red, tid);
    float mu = ssum * (1.f / SDIM);
    float var = ssq * (1.f / SDIM) - mu * mu;
    float rstd = rsqrtf(var + 1e-5f);
    hnext[(size_t)n * FEAT + tid] = (sn - mu) * rstd * (1.f + ada[tid]) + ada[SDIM + tid];

    // vnorms
    float q1 = (tid < 96) ? vbuf[tid] * vbuf[tid] : 0.f;
    float S1 = block_reduce_sum(q1, red, tid);
    float q2 = (tid >= 96 && tid < 192) ? vbuf[tid] * vbuf[tid] : 0.f;
    float S2 = block_reduce_sum(q2, red, tid);
    float q3 = (tid < 80) ? vbuf[192 + tid] * vbuf[192 + tid] : 0.f;
    float S3 = block_reduce_sum(q3, red, tid);

    float r1 = rsqrtf(S1 * (1.f / VDIM) + 1e-5f);
    float r2 = rsqrtf(S2 * (1.f / VDIM) + 1e-5f);
    float r3 = rsqrtf(S3 * (1.f / L2DIM) + 1e-5f);

    if (tid < 96) {
        int d = tid / 3;
        hnext[(size_t)n * FEAT + SDIM + tid] = vbuf[tid] * r1 * (1.f + ada[2*SDIM + d]);
    } else if (tid < 192) {
        int t2 = tid - 96;
        int d = t2 / 3;
        hnext[(size_t)n * FEAT + SDIM + 3*VDIM + t2] = vbuf[tid] * r2 * (1.f + ada[2*SDIM + VDIM + d]);
    }
    if (tid < 80) {
        int d = tid / 5;
        hnext[(size_t)n * FEAT + SDIM + 6*VDIM + tid] = vbuf[192 + tid] * r3 * (1.f + ada[2*SDIM + 2*VDIM + d]);
    }
}

// ---------------------------------------------------------------- launch
extern "C" void kernel_launch(void* const* d_in, const int* in_sizes, int n_in,
                              void* d_out, int out_size, void* d_ws, size_t ws_size,
                              hipStream_t stream) {
    const float* h_in   = (const float*)d_in[0];
    const float* coords = (const float*)d_in[1];
    const float* erd    = (const float*)d_in[2];
    const float* t_emb  = (const float*)d_in[3];
    const float* etype_emb   = (const float*)d_in[4];
    const float* btype_emb   = (const float*)d_in[5];
    const float* bconj_emb   = (const float*)d_in[6];
    const float* bring_emb   = (const float*)d_in[7];
    const float* bstereo_emb = (const float*)d_in[8];
    const float* refW   = (const float*)d_in[9];
    const float* refb   = (const float*)d_in[10];
    const float* edgeW  = (const float*)d_in[11];
    const float* edgeb  = (const float*)d_in[12];
    const float* svW    = (const float*)d_in[13];
    const float* proj_s = (const float*)d_in[14];
    const float* proj_v1= (const float*)d_in[15];
    const float* proj_v2= (const float*)d_in[16];
    const float* proj_l2= (const float*)d_in[17];
    const float* adaW   = (const float*)d_in[18];
    const float* adab   = (const float*)d_in[19];
    const int* eidx     = (const int*)d_in[20];
    const int* etype    = (const int*)d_in[21];
    const int* ebt      = (const int*)d_in[22];
    const int* ebc      = (const int*)d_in[23];
    const int* ebr      = (const int*)d_in[24];
    const int* ebs      = (const int*)d_in[25];

    float* ws_f    = (float*)d_ws;
    float* sv      = ws_f;                       // N*32
    float* agg_s   = sv + (size_t)NN * VDIM;     // N*256
    float* agg_v1o = agg_s + (size_t)NN * SDIM;  // N*96
    float* agg_v1e = agg_v1o + (size_t)NN * 96;  // N*96
    float* agg_l2  = agg_v1e + (size_t)NN * 96;  // N*80
    float* h1      = agg_l2 + (size_t)NN * 80;   // N*528

    for (int l = 0; l < 2; ++l) {
        const float* hcur = (l == 0) ? h_in : h1;
        float* hnext      = (l == 0) ? h1 : (float*)d_out;

        hipMemsetAsync(agg_s, 0, (size_t)NN * FEAT * sizeof(float), stream);
        sv_kernel<<<(NN * VDIM + 255) / 256, 256, 0, stream>>>(hcur, svW + l * SDIM * VDIM, sv);
        edge_kernel<<<NE / ET, 256, 0, stream>>>(
            hcur, t_emb, coords, erd, sv,
            edgeW + (size_t)l * ESD * WOUT, edgeb + l * WOUT,
            eidx, etype, ebt, ebc, ebr, ebs,
            etype_emb + l * 144, btype_emb + l * 48, bconj_emb + l * 12,
            bring_emb + l * 12, bstereo_emb + l * 20,
            refW + l * 24, refb + l * 8,
            agg_s, agg_v1o, agg_v1e, agg_l2);
        node_kernel<<<NN, 256, 0, stream>>>(
            hcur, t_emb, agg_s, agg_v1o, agg_v1e, agg_l2,
            proj_s + (size_t)l * SDIM * SDIM, proj_v1 + l * VDIM * VDIM,
            proj_v2 + l * VDIM * VDIM, proj_l2 + l * L2DIM * L2DIM,
            adaW + (size_t)l * TDIM * ADA, adab + l * ADA,
            hnext);
    }
}

// Round 2
// 3398.616 us; speedup vs baseline: 1.3083x; 1.3083x over previous
//
#include <hip/hip_runtime.h>
#include <math.h>

#define NN 10000
#define NE 160000
#define SDIM 256
#define VDIM 32
#define L2DIM 16
#define TDIM 128
#define FEAT 528      // S + 3V + 3V + 5*L2
#define WOUT 400      // S + 4V + L2
#define ESD 700       // 16+16+20+8+S+S+TDIM
#define KP 704        // ESD padded to multiple of 32
#define ADA 592       // 2S+2V+L2
#define DEG_INV 0.25f

#define ETM 32        // edges per block
#define AP 712        // A-LDS stride in bf16 (1424B: 2-way LDS conflicts only)
#define WLP 412       // w LDS stride in f32 (2-way on write)

typedef short bf16x8 __attribute__((ext_vector_type(8)));
typedef float f32x4 __attribute__((ext_vector_type(4)));

__device__ __forceinline__ unsigned short f2bf(float f) {
    unsigned int u = __float_as_uint(f);
    u += 0x7fffu + ((u >> 16) & 1u);      // round-to-nearest-even
    return (unsigned short)(u >> 16);
}

// -------------------------------------------------- Wt = bf16(edge_W^T), K-padded
__global__ __launch_bounds__(256) void wt_kernel(const float* __restrict__ W,
                                                 unsigned short* __restrict__ Wt) {
    int c = blockIdx.y;
    int k = blockIdx.x * 256 + threadIdx.x;
    if (k >= KP) return;
    float v = (k < ESD) ? W[(size_t)k * WOUT + c] : 0.f;
    Wt[(size_t)c * KP + k] = f2bf(v);
}

// -------------------------------------------------- sv = s @ sv_W
__global__ __launch_bounds__(256) void sv_kernel(const float* __restrict__ hcur,
                                                 const float* __restrict__ svW,
                                                 float* __restrict__ sv) {
    int i = blockIdx.x * 256 + threadIdx.x;
    if (i >= NN * VDIM) return;
    int n = i >> 5, v = i & 31;
    const float* hs = hcur + (size_t)n * FEAT;
    float acc = 0.f;
    for (int k = 0; k < SDIM; ++k) acc = fmaf(hs[k], svW[k * VDIM + v], acc);
    sv[i] = acc;
}

// -------------------------------------------------- edge kernel (MFMA GEMM + messages)
__global__ __launch_bounds__(256) void edge_kernel(
    const float* __restrict__ hcur, const float* __restrict__ t_emb,
    const float* __restrict__ coords, const float* __restrict__ erd,
    const float* __restrict__ sv,
    const unsigned short* __restrict__ Wt, const float* __restrict__ bvec,
    const int* __restrict__ eidx,
    const int* __restrict__ etype, const int* __restrict__ ebt,
    const int* __restrict__ ebc, const int* __restrict__ ebr,
    const int* __restrict__ ebs,
    const float* __restrict__ etype_emb, const float* __restrict__ btype_emb,
    const float* __restrict__ bconj_emb, const float* __restrict__ bring_emb,
    const float* __restrict__ bstereo_emb,
    const float* __restrict__ refW, const float* __restrict__ refb,
    float* __restrict__ agg_s, float* __restrict__ agg_v1o,
    float* __restrict__ agg_v1e, float* __restrict__ agg_l2)
{
    __shared__ __align__(16) char smem_raw[ETM * WLP * 4];   // 52736 B
    unsigned short* As = (unsigned short*)smem_raw;          // [ETM][AP] bf16 scalars
    float* wl = (float*)smem_raw;                            // [ETM][WLP] f32 w (reuse)

    __shared__ int   srcl[ETM], dstl[ETM];
    __shared__ float y1l[ETM][3];

    const int tid = threadIdx.x;
    const int e0  = blockIdx.x * ETM;

    __shared__ int   itype[ETM], ibt[ETM], ibc[ETM], ibr[ETM], ibs[ETM];
    __shared__ float distl[ETM], erdl[ETM];

    if (tid < ETM) {
        int ge = e0 + tid;
        int s = eidx[ge], d = eidx[NE + ge];
        srcl[tid] = s; dstl[tid] = d;
        itype[tid] = etype[ge]; ibt[tid] = ebt[ge]; ibc[tid] = ebc[ge];
        ibr[tid] = ebr[ge]; ibs[tid] = ebs[ge];
        float dx = coords[d*3+0] - coords[s*3+0];
        float dy = coords[d*3+1] - coords[s*3+1];
        float dz = coords[d*3+2] - coords[s*3+2];
        float dist = sqrtf(dx*dx + dy*dy + dz*dz);
        distl[tid] = dist;
        float inv = 1.f / (dist + 1e-8f);
        y1l[tid][0] = dx * inv; y1l[tid][1] = dy * inv; y1l[tid][2] = dz * inv;
        erdl[tid] = erd[ge];
    }
    __syncthreads();

    // ---- build edge_scalars (bf16) in LDS
    for (int e = 0; e < ETM; ++e) {
        const int src = srcl[e], dst = dstl[e];
        const float* hs = hcur + (size_t)src * FEAT;
        const float* hd = hcur + (size_t)dst * FEAT;
        const float* td = t_emb + (size_t)dst * TDIM;
        const float de = distl[e];
        for (int k = tid; k < KP; k += 256) {
            float v;
            if (k >= ESD) v = 0.f;
            else if (k < 16) { float x = (de - (float)k * (10.f/15.f)) * 1.6f; v = expf(-x*x); }
            else if (k < 32) v = etype_emb[itype[e]*16 + (k-16)];
            else if (k < 40) v = btype_emb[ibt[e]*8 + (k-32)];
            else if (k < 44) v = bconj_emb[ibc[e]*4 + (k-40)];
            else if (k < 48) v = bring_emb[ibr[e]*4 + (k-44)];
            else if (k < 52) v = bstereo_emb[ibs[e]*4 + (k-48)];
            else if (k < 60) {
                int j = k - 52;
                float dd = de - erdl[e];
                float hr = erdl[e] > 0.f ? 1.f : 0.f;
                v = fabsf(dd)*refW[j] + dd*refW[8+j] + hr*refW[16+j] + refb[j];
            }
            else if (k < 60 + SDIM)     v = hs[k - 60];
            else if (k < 60 + 2*SDIM)   v = hd[k - 316];
            else                        v = td[k - 572];
            As[e * AP + k] = f2bf(v);
        }
    }
    __syncthreads();

    // ---- MFMA GEMM: 32 edges x 400 cols, K=704
    // 4 waves, wave w owns N-tiles [6w, 6w+7) (overlaps recompute same values)
    const int wid  = tid >> 6;
    const int lane = tid & 63;
    const int lr   = lane & 15;           // A row / B col within tile
    const int lkb  = (lane >> 4) << 3;    // k base within 32-step: 0,8,16,24
    const int nt0  = wid * 6;

    f32x4 acc[2][7];
    #pragma unroll
    for (int m = 0; m < 2; ++m)
        #pragma unroll
        for (int t = 0; t < 7; ++t) acc[m][t] = (f32x4){0.f, 0.f, 0.f, 0.f};

    for (int ks = 0; ks < KP / 32; ++ks) {
        const int kb = ks * 32 + lkb;
        bf16x8 a0 = *(const bf16x8*)&As[(lr)      * AP + kb];
        bf16x8 a1 = *(const bf16x8*)&As[(16 + lr) * AP + kb];
        #pragma unroll
        for (int t = 0; t < 7; ++t) {
            bf16x8 bf = *(const bf16x8*)&Wt[(size_t)((nt0 + t) * 16 + lr) * KP + kb];
            acc[0][t] = __builtin_amdgcn_mfma_f32_16x16x32_bf16(a0, bf, acc[0][t], 0, 0, 0);
            acc[1][t] = __builtin_amdgcn_mfma_f32_16x16x32_bf16(a1, bf, acc[1][t], 0, 0, 0);
        }
    }
    __syncthreads();   // everyone done reading As; LDS becomes w

    // write w = acc + bias into LDS: C/D layout col=lane&15, row=(lane>>4)*4+reg
    {
        const int rbase = (lane >> 4) << 2;
        #pragma unroll
        for (int t = 0; t < 7; ++t) {
            const int col = (nt0 + t) * 16 + lr;
            const float b = bvec[col];
            #pragma unroll
            for (int m = 0; m < 2; ++m) {
                #pragma unroll
                for (int r = 0; r < 4; ++r) {
                    int erow = m * 16 + rbase + r;
                    wl[erow * WLP + col] = acc[m][t][r] + b;
                }
            }
        }
    }
    __syncthreads();

    // ---- scalar messages: m_s = w_s * s[src]
    {
        const int c1 = tid;
        for (int e = 0; e < ETM; ++e) {
            const int src = srcl[e], dst = dstl[e];
            float ms = wl[e * WLP + c1] * hcur[(size_t)src * FEAT + c1];
            atomicAdd(&agg_s[(size_t)dst * SDIM + c1], ms);
        }
    }

    // ---- vector messages: 32 edges x 32 ch = 1024 items, 4 rounds
    for (int r = 0; r < 4; ++r) {
        int it = r * 256 + tid;
        int e = it >> 5, c = it & 31;
        const int src = srcl[e], dst = dstl[e];
        float wv1 = wl[e * WLP + SDIM + c];
        float wsv = wl[e * WLP + SDIM + VDIM + c];
        float wv2 = wl[e * WLP + SDIM + 2*VDIM + c];
        float wcx = wl[e * WLP + SDIM + 3*VDIM + c];
        float svv = sv[(size_t)src * VDIM + c];
        const float* vo = hcur + (size_t)src * FEAT + SDIM + c*3;
        const float* ve = hcur + (size_t)src * FEAT + SDIM + 3*VDIM + c*3;
        float y0 = y1l[e][0], y1 = y1l[e][1], y2 = y1l[e][2];
        float a0 = vo[0], a1 = vo[1], a2 = vo[2];
        float cx0 = a1*y2 - a2*y1;
        float cx1 = a2*y0 - a0*y2;
        float cx2 = a0*y1 - a1*y0;
        float t = wsv * svv;
        float* po = &agg_v1o[(size_t)dst * 3*VDIM + c*3];
        float* pe = &agg_v1e[(size_t)dst * 3*VDIM + c*3];
        atomicAdd(po + 0, wv1*a0 + t*y0);
        atomicAdd(po + 1, wv1*a1 + t*y1);
        atomicAdd(po + 2, wv1*a2 + t*y2);
        atomicAdd(pe + 0, wv2*ve[0] + wcx*cx0);
        atomicAdd(pe + 1, wv2*ve[1] + wcx*cx1);
        atomicAdd(pe + 2, wv2*ve[2] + wcx*cx2);
    }

    // ---- l2 messages: 32 edges x 16 ch = 512 items, 2 rounds
    for (int r = 0; r < 2; ++r) {
        int it = r * 256 + tid;
        int e = it >> 4, c = it & 15;
        const int src = srcl[e], dst = dstl[e];
        float w2 = wl[e * WLP + SDIM + 4*VDIM + c];
        const float* q = hcur + (size_t)src * FEAT + SDIM + 6*VDIM + c*5;
        float* pq = &agg_l2[(size_t)dst * 5*L2DIM + c*5];
        #pragma unroll
        for (int i = 0; i < 5; ++i) atomicAdd(pq + i, w2 * q[i]);
    }
}

// ---------------------------------------------------------------- node kernel
__device__ __forceinline__ float block_reduce_sum(float v, float* red, int tid) {
    #pragma unroll
    for (int off = 32; off > 0; off >>= 1) v += __shfl_down(v, off, 64);
    if ((tid & 63) == 0) red[tid >> 6] = v;
    __syncthreads();
    float s = red[0] + red[1] + red[2] + red[3];
    __syncthreads();
    return s;
}

__global__ __launch_bounds__(256) void node_kernel(
    const float* __restrict__ hcur, const float* __restrict__ t_emb,
    const float* __restrict__ agg_s, const float* __restrict__ agg_v1o,
    const float* __restrict__ agg_v1e, const float* __restrict__ agg_l2,
    const float* __restrict__ proj_s, const float* __restrict__ proj_v1,
    const float* __restrict__ proj_v2, const float* __restrict__ proj_l2,
    const float* __restrict__ adaW, const float* __restrict__ adab,
    float* __restrict__ hnext)
{
    const int n = blockIdx.x;
    const int tid = threadIdx.x;
    __shared__ float a_s[SDIM];
    __shared__ float te[TDIM];
    __shared__ float ada[ADA];
    __shared__ float av[272];    // 96 v1o + 96 v1e + 80 l2 (scaled aggs)
    __shared__ float vbuf[272];  // residual-added values before norm
    __shared__ float red[8];

    a_s[tid] = agg_s[(size_t)n * SDIM + tid] * DEG_INV;
    if (tid < TDIM) te[tid] = t_emb[(size_t)n * TDIM + tid];
    for (int i = tid; i < 272; i += 256) {
        float val;
        if (i < 96)        val = agg_v1o[(size_t)n * 96 + i];
        else if (i < 192)  val = agg_v1e[(size_t)n * 96 + (i - 96)];
        else               val = agg_l2[(size_t)n * 80 + (i - 192)];
        av[i] = val * DEG_INV;
    }
    __syncthreads();

    // ada = t_emb @ ada_W + ada_b
    for (int r = 0; r < 3; ++r) {
        int col = r * 256 + tid;
        if (col < ADA) {
            float acc = adab[col];
            for (int k = 0; k < TDIM; ++k) acc = fmaf(te[k], adaW[(size_t)k * ADA + col], acc);
            ada[col] = acc;
        }
    }

    // u_s = silu(agg_s @ proj_s); s_new = s + u_s
    float acc = 0.f;
    for (int k = 0; k < SDIM; ++k) acc = fmaf(a_s[k], proj_s[(size_t)k * SDIM + tid], acc);
    float us = acc / (1.f + expf(-acc));
    float sn = hcur[(size_t)n * FEAT + tid] + us;

    // vector/l2 proj + residual
    if (tid < 96) {
        int d = tid / 3, i = tid - d * 3;
        float a = 0.f;
        #pragma unroll
        for (int c = 0; c < VDIM; ++c) a = fmaf(av[c*3 + i], proj_v1[c * VDIM + d], a);
        vbuf[tid] = hcur[(size_t)n * FEAT + SDIM + tid] + a;
    } else if (tid < 192) {
        int t2 = tid - 96;
        int d = t2 / 3, i = t2 - d * 3;
        float a = 0.f;
        #pragma unroll
        for (int c = 0; c < VDIM; ++c) a = fmaf(av[96 + c*3 + i], proj_v2[c * VDIM + d], a);
        vbuf[tid] = hcur[(size_t)n * FEAT + SDIM + 3*VDIM + t2] + a;
    }
    if (tid < 80) {
        int d = tid / 5, i = tid - d * 5;
        float a = 0.f;
        #pragma unroll
        for (int c = 0; c < L2DIM; ++c) a = fmaf(av[192 + c*5 + i], proj_l2[c * L2DIM + d], a);
        vbuf[192 + tid] = hcur[(size_t)n * FEAT + SDIM + 6*VDIM + tid] + a;
    }
    __syncthreads();

    // LayerNorm on s
    float ssum = block_reduce_sum(sn, red, tid);
    float ssq  = block_reduce_sum(sn * sn, red, tid);
    float mu = ssum * (1.f / SDIM);
    float var = ssq * (1.f / SDIM) - mu * mu;
    float rstd = rsqrtf(var + 1e-5f);
    hnext[(size_t)n * FEAT + tid] = (sn - mu) * rstd * (1.f + ada[tid]) + ada[SDIM + tid];

    // vnorms
    float q1 = (tid < 96) ? vbuf[tid] * vbuf[tid] : 0.f;
    float S1 = block_reduce_sum(q1, red, tid);
    float q2 = (tid >= 96 && tid < 192) ? vbuf[tid] * vbuf[tid] : 0.f;
    float S2 = block_reduce_sum(q2, red, tid);
    float q3 = (tid < 80) ? vbuf[192 + tid] * vbuf[192 + tid] : 0.f;
    float S3 = block_reduce_sum(q3, red, tid);

    float r1 = rsqrtf(S1 * (1.f / VDIM) + 1e-5f);
    float r2 = rsqrtf(S2 * (1.f / VDIM) + 1e-5f);
    float r3 = rsqrtf(S3 * (1.f / L2DIM) + 1e-5f);

    if (tid < 96) {
        int d = tid / 3;
        hnext[(size_t)n * FEAT + SDIM + tid] = vbuf[tid] * r1 * (1.f + ada[2*SDIM + d]);
    } else if (tid < 192) {
        int t2 = tid - 96;
        int d = t2 / 3;
        hnext[(size_t)n * FEAT + SDIM + 3*VDIM + t2] = vbuf[tid] * r2 * (1.f + ada[2*SDIM + VDIM + d]);
    }
    if (tid < 80) {
        int d = tid / 5;
        hnext[(size_t)n * FEAT + SDIM + 6*VDIM + tid] = vbuf[192 + tid] * r3 * (1.f + ada[2*SDIM + 2*VDIM + d]);
    }
}

// ---------------------------------------------------------------- launch
extern "C" void kernel_launch(void* const* d_in, const int* in_sizes, int n_in,
                              void* d_out, int out_size, void* d_ws, size_t ws_size,
                              hipStream_t stream) {
    const float* h_in   = (const float*)d_in[0];
    const float* coords = (const float*)d_in[1];
    const float* erd    = (const float*)d_in[2];
    const float* t_emb  = (const float*)d_in[3];
    const float* etype_emb   = (const float*)d_in[4];
    const float* btype_emb   = (const float*)d_in[5];
    const float* bconj_emb   = (const float*)d_in[6];
    const float* bring_emb   = (const float*)d_in[7];
    const float* bstereo_emb = (const float*)d_in[8];
    const float* refW   = (const float*)d_in[9];
    const float* refb   = (const float*)d_in[10];
    const float* edgeW  = (const float*)d_in[11];
    const float* edgeb  = (const float*)d_in[12];
    const float* svW    = (const float*)d_in[13];
    const float* proj_s = (const float*)d_in[14];
    const float* proj_v1= (const float*)d_in[15];
    const float* proj_v2= (const float*)d_in[16];
    const float* proj_l2= (const float*)d_in[17];
    const float* adaW   = (const float*)d_in[18];
    const float* adab   = (const float*)d_in[19];
    const int* eidx     = (const int*)d_in[20];
    const int* etype    = (const int*)d_in[21];
    const int* ebt      = (const int*)d_in[22];
    const int* ebc      = (const int*)d_in[23];
    const int* ebr      = (const int*)d_in[24];
    const int* ebs      = (const int*)d_in[25];

    float* ws_f    = (float*)d_ws;
    float* sv      = ws_f;                       // N*32
    float* agg_s   = sv + (size_t)NN * VDIM;     // N*256
    float* agg_v1o = agg_s + (size_t)NN * SDIM;  // N*96
    float* agg_v1e = agg_v1o + (size_t)NN * 96;  // N*96
    float* agg_l2  = agg_v1e + (size_t)NN * 96;  // N*80
    float* h1      = agg_l2 + (size_t)NN * 80;   // N*528
    unsigned short* Wt = (unsigned short*)(h1 + (size_t)NN * FEAT);  // 400*704 bf16

    for (int l = 0; l < 2; ++l) {
        const float* hcur = (l == 0) ? h_in : h1;
        float* hnext      = (l == 0) ? h1 : (float*)d_out;

        hipMemsetAsync(agg_s, 0, (size_t)NN * FEAT * sizeof(float), stream);
        wt_kernel<<<dim3(3, WOUT), 256, 0, stream>>>(edgeW + (size_t)l * ESD * WOUT, Wt);
        sv_kernel<<<(NN * VDIM + 255) / 256, 256, 0, stream>>>(hcur, svW + l * SDIM * VDIM, sv);
        edge_kernel<<<NE / ETM, 256, 0, stream>>>(
            hcur, t_emb, coords, erd, sv,
            Wt, edgeb + l * WOUT,
            eidx, etype, ebt, ebc, ebr, ebs,
            etype_emb + l * 144, btype_emb + l * 48, bconj_emb + l * 12,
            bring_emb + l * 12, bstereo_emb + l * 20,
            refW + l * 24, refb + l * 8,
            agg_s, agg_v1o, agg_v1e, agg_l2);
        node_kernel<<<NN, 256, 0, stream>>>(
            hcur, t_emb, agg_s, agg_v1o, agg_v1e, agg_l2,
            proj_s + (size_t)l * SDIM * SDIM, proj_v1 + l * VDIM * VDIM,
            proj_v2 + l * VDIM * VDIM, proj_l2 + l * L2DIM * L2DIM,
            adaW + (size_t)l * TDIM * ADA, adab + l * ADA,
            hnext);
    }
}

// Round 4
// 1705.522 us; speedup vs baseline: 2.6070x; 1.9927x over previous
//
#include <hip/hip_runtime.h>
#include <math.h>

#define NN 10000
#define NE 160000
#define SDIM 256
#define VDIM 32
#define L2DIM 16
#define TDIM 128
#define FEAT 528      // S + 3V + 3V + 5*L2
#define WOUT 400      // S + 4V + L2
#define ADA 592       // 2S+2V+L2
#define DEG_INV 0.25f

#define ETM 32        // edges per block
#define WLP 404       // w LDS stride (f32)
#define AP1 72        // misc A stride (bf16)
#define AP2 392       // nodeproj A stride (bf16)

typedef short bf16x8 __attribute__((ext_vector_type(8)));
typedef float f32x4 __attribute__((ext_vector_type(4)));

__device__ __forceinline__ unsigned short f2bf(float f) {
    unsigned int u = __float_as_uint(f);
    u += 0x7fffu + ((u >> 16) & 1u);      // round-to-nearest-even
    return (unsigned short)(u >> 16);
}

// ================================================================ sort by dst
__global__ __launch_bounds__(256) void hist_kernel(const int* __restrict__ eidx,
                                                   int* __restrict__ cnt) {
    int e = blockIdx.x * 256 + threadIdx.x;
    if (e < NE) atomicAdd(&cnt[eidx[NE + e]], 1);
}

__global__ __launch_bounds__(1024) void scan_kernel(const int* __restrict__ cnt,
                                                    int* __restrict__ cursor) {
    __shared__ int sc[1024];
    int tid = threadIdx.x;
    int base = tid * 10;
    int loc[10];
    int s = 0;
    if (base < NN) {
        #pragma unroll
        for (int j = 0; j < 10; ++j) { loc[j] = cnt[base + j]; s += loc[j]; }
    }
    sc[tid] = s;
    __syncthreads();
    for (int off = 1; off < 1024; off <<= 1) {
        int v = sc[tid];
        int add = (tid >= off) ? sc[tid - off] : 0;
        __syncthreads();
        sc[tid] = v + add;
        __syncthreads();
    }
    int run = sc[tid] - s;   // exclusive prefix
    if (base < NN) {
        #pragma unroll
        for (int j = 0; j < 10; ++j) { cursor[base + j] = run; run += loc[j]; }
    }
}

__global__ __launch_bounds__(256) void scatter_kernel(const int* __restrict__ eidx,
                                                      int* __restrict__ cursor,
                                                      int* __restrict__ perm) {
    int e = blockIdx.x * 256 + threadIdx.x;
    if (e < NE) {
        int d = eidx[NE + e];
        int p = atomicAdd(&cursor[d], 1);
        perm[p] = e;
    }
}

// ================================================================ weight prep
// Wt1[c][k] = bf16(edge_W[k][c]) for k<60 (pad to 64)
__global__ __launch_bounds__(256) void wt1_kernel(const float* __restrict__ W,
                                                  unsigned short* __restrict__ Wt1) {
    int idx = blockIdx.x * 256 + threadIdx.x;      // 400*64 items
    if (idx >= WOUT * 64) return;
    int c = idx >> 6, k = idx & 63;
    float v = (k < 60) ? W[(size_t)k * WOUT + c] : 0.f;
    Wt1[idx] = f2bf(v);
}

// Bn[c][k], c<400: srcW slice (W rows 60..315); c>=400: dstW slice (W rows 316..571 + t rows 572..699)
__global__ __launch_bounds__(256) void bnode_kernel(const float* __restrict__ W,
                                                    unsigned short* __restrict__ Bn) {
    int k = blockIdx.x * 256 + threadIdx.x;
    if (k >= 384) return;
    int c = blockIdx.y;
    float v;
    if (c < WOUT) v = (k < 256) ? W[(size_t)(60 + k) * WOUT + c] : 0.f;
    else {
        int c2 = c - WOUT;
        v = (k < 256) ? W[(size_t)(316 + k) * WOUT + c2]
                      : W[(size_t)(572 + (k - 256)) * WOUT + c2];
    }
    Bn[(size_t)c * 384 + k] = f2bf(v);
}

// ================================================================ sv = s @ sv_W
__global__ __launch_bounds__(256) void sv_kernel(const float* __restrict__ hcur,
                                                 const float* __restrict__ svW,
                                                 float* __restrict__ sv) {
    int i = blockIdx.x * 256 + threadIdx.x;
    if (i >= NN * VDIM) return;
    int n = i >> 5, v = i & 31;
    const float* hs = hcur + (size_t)n * FEAT;
    float acc = 0.f;
    for (int k = 0; k < SDIM; ++k) acc = fmaf(hs[k], svW[k * VDIM + v], acc);
    sv[i] = acc;
}

// ================================================================ nodeproj: srcdst[n][800]
__global__ __launch_bounds__(256) void nodeproj_kernel(
    const float* __restrict__ hcur, const float* __restrict__ t_emb,
    const unsigned short* __restrict__ Bn, const float* __restrict__ edge_b,
    float* __restrict__ srcdst)
{
    __shared__ unsigned short As2[32 * AP2];
    const int tid = threadIdx.x;
    const int n0 = blockIdx.x * 32;

    for (int e = 0; e < 32; ++e) {
        int n = n0 + e;
        float v0 = (n < NN) ? hcur[(size_t)n * FEAT + tid] : 0.f;
        As2[e * AP2 + tid] = f2bf(v0);
        if (tid < 128) {
            float v1 = (n < NN) ? t_emb[(size_t)n * TDIM + tid] : 0.f;
            As2[e * AP2 + 256 + tid] = f2bf(v1);
        }
    }
    __syncthreads();

    const int wid = tid >> 6, lane = tid & 63;
    const int lr = lane & 15, lkb = (lane >> 4) << 3;
    const int nt0 = wid * 13;                 // 50 tiles over 4 waves (52 slots, clamp)

    f32x4 acc[2][13];
    #pragma unroll
    for (int m = 0; m < 2; ++m)
        #pragma unroll
        for (int t = 0; t < 13; ++t) acc[m][t] = (f32x4){0.f, 0.f, 0.f, 0.f};

    for (int ks = 0; ks < 12; ++ks) {
        int kb = ks * 32 + lkb;
        bf16x8 a0 = *(const bf16x8*)&As2[lr * AP2 + kb];
        bf16x8 a1 = *(const bf16x8*)&As2[(16 + lr) * AP2 + kb];
        #pragma unroll
        for (int t = 0; t < 13; ++t) {
            int tile = nt0 + t;
            if (tile < 50) {
                bf16x8 b = *(const bf16x8*)&Bn[(size_t)(tile * 16 + lr) * 384 + kb];
                acc[0][t] = __builtin_amdgcn_mfma_f32_16x16x32_bf16(a0, b, acc[0][t], 0, 0, 0);
                acc[1][t] = __builtin_amdgcn_mfma_f32_16x16x32_bf16(a1, b, acc[1][t], 0, 0, 0);
            }
        }
    }

    const int rbase = (lane >> 4) << 2;
    #pragma unroll
    for (int t = 0; t < 13; ++t) {
        int tile = nt0 + t;
        if (tile < 50) {
            int col = tile * 16 + lr;
            float badd = (col >= WOUT) ? edge_b[col - WOUT] : 0.f;
            #pragma unroll
            for (int m = 0; m < 2; ++m) {
                #pragma unroll
                for (int r = 0; r < 4; ++r) {
                    int n = n0 + m * 16 + rbase + r;
                    if (n < NN) srcdst[(size_t)n * 800 + col] = acc[m][t][r] + badd;
                }
            }
        }
    }
}

// ================================================================ edge kernel
__global__ __launch_bounds__(256) void edge_kernel(
    const float* __restrict__ hcur, const float* __restrict__ coords,
    const float* __restrict__ erd, const float* __restrict__ sv,
    const unsigned short* __restrict__ Wt1, const float* __restrict__ srcdst,
    const int* __restrict__ perm, const int* __restrict__ eidx,
    const int* __restrict__ etype, const int* __restrict__ ebt,
    const int* __restrict__ ebc, const int* __restrict__ ebr,
    const int* __restrict__ ebs,
    const float* __restrict__ etype_emb, const float* __restrict__ btype_emb,
    const float* __restrict__ bconj_emb, const float* __restrict__ bring_emb,
    const float* __restrict__ bstereo_emb,
    const float* __restrict__ refW, const float* __restrict__ refb,
    float* __restrict__ agg)
{
    __shared__ float wl[ETM * WLP];              // 51.7 KB
    __shared__ unsigned short As[ETM * AP1];     // 4.6 KB
    __shared__ int srcl[ETM], dstl[ETM];
    __shared__ int itype[ETM], ibt[ETM], ibc[ETM], ibr[ETM], ibs[ETM];
    __shared__ float distl[ETM], erdl[ETM], y1l[ETM][3];

    const int tid = threadIdx.x;
    const int e0 = blockIdx.x * ETM;

    if (tid < ETM) {
        int ge = perm[e0 + tid];
        int s = eidx[ge], d = eidx[NE + ge];
        srcl[tid] = s; dstl[tid] = d;
        itype[tid] = etype[ge]; ibt[tid] = ebt[ge]; ibc[tid] = ebc[ge];
        ibr[tid] = ebr[ge]; ibs[tid] = ebs[ge];
        float dx = coords[d*3+0] - coords[s*3+0];
        float dy = coords[d*3+1] - coords[s*3+1];
        float dz = coords[d*3+2] - coords[s*3+2];
        float dist = sqrtf(dx*dx + dy*dy + dz*dz);
        distl[tid] = dist;
        float inv = 1.f / (dist + 1e-8f);
        y1l[tid][0] = dx * inv; y1l[tid][1] = dy * inv; y1l[tid][2] = dz * inv;
        erdl[tid] = erd[ge];
    }
    __syncthreads();

    // ---- stage misc features (k<60, padded to 64) as bf16
    {
        const int k = tid & 63;
        const int ebase = tid >> 6;
        for (int it = 0; it < 8; ++it) {
            int e = it * 4 + ebase;
            float de = distl[e];
            float v;
            if (k >= 60) v = 0.f;
            else if (k < 16) { float x = (de - (float)k * (10.f/15.f)) * 1.6f; v = expf(-x*x); }
            else if (k < 32) v = etype_emb[itype[e]*16 + (k-16)];
            else if (k < 40) v = btype_emb[ibt[e]*8 + (k-32)];
            else if (k < 44) v = bconj_emb[ibc[e]*4 + (k-40)];
            else if (k < 48) v = bring_emb[ibr[e]*4 + (k-44)];
            else if (k < 52) v = bstereo_emb[ibs[e]*4 + (k-48)];
            else {
                int j = k - 52;
                float dd = de - erdl[e];
                float hr = erdl[e] > 0.f ? 1.f : 0.f;
                v = fabsf(dd)*refW[j] + dd*refW[8+j] + hr*refW[16+j] + refb[j];
            }
            As[e * AP1 + k] = f2bf(v);
        }
    }
    __syncthreads();

    // ---- tiny MFMA GEMM: misc(64) x W1 -> wl (f32, no bias)
    const int wid = tid >> 6, lane = tid & 63;
    const int lr = lane & 15, lkb = (lane >> 4) << 3;
    const int nt0 = wid * 6;                  // 25 tiles / 4 waves, 7 each (overlap dup)
    {
        f32x4 acc[2][7];
        #pragma unroll
        for (int m = 0; m < 2; ++m)
            #pragma unroll
            for (int t = 0; t < 7; ++t) acc[m][t] = (f32x4){0.f, 0.f, 0.f, 0.f};

        #pragma unroll
        for (int ks = 0; ks < 2; ++ks) {
            int kb = ks * 32 + lkb;
            bf16x8 a0 = *(const bf16x8*)&As[lr * AP1 + kb];
            bf16x8 a1 = *(const bf16x8*)&As[(16 + lr) * AP1 + kb];
            #pragma unroll
            for (int t = 0; t < 7; ++t) {
                bf16x8 b = *(const bf16x8*)&Wt1[(size_t)((nt0 + t) * 16 + lr) * 64 + kb];
                acc[0][t] = __builtin_amdgcn_mfma_f32_16x16x32_bf16(a0, b, acc[0][t], 0, 0, 0);
                acc[1][t] = __builtin_amdgcn_mfma_f32_16x16x32_bf16(a1, b, acc[1][t], 0, 0, 0);
            }
        }
        const int rbase = (lane >> 4) << 2;
        #pragma unroll
        for (int t = 0; t < 7; ++t) {
            const int col = (nt0 + t) * 16 + lr;
            #pragma unroll
            for (int m = 0; m < 2; ++m)
                #pragma unroll
                for (int r = 0; r < 4; ++r)
                    wl[(m * 16 + rbase + r) * WLP + col] = acc[m][t][r];
        }
    }
    __syncthreads();

    // ---- add per-node projections: w += srcW[src] + dstW[dst] (bias folded in dstW)
    for (int e = 0; e < ETM; ++e) {
        const int s_ = srcl[e], d_ = dstl[e];
        wl[e * WLP + tid] += srcdst[(size_t)s_ * 800 + tid] + srcdst[(size_t)d_ * 800 + 400 + tid];
        if (tid < 144)
            wl[e * WLP + 256 + tid] += srcdst[(size_t)s_ * 800 + 256 + tid] + srcdst[(size_t)d_ * 800 + 656 + tid];
    }
    __syncthreads();

    // ---- messages with run-accumulation (edges sorted by dst)
    // B-channel space: 272 = 96 v1o + 96 v1e + 80 l2. tids 0..255 own channels
    // 0..255; tids 0..15 additionally own l2 channels 64..79 (accC).
    {
        int cls = 0, cc = 0, ii = 0, ia = 0, ib = 0, hoff = 0, wB1 = 0, wB2 = 0;
        if (tid < 96)       { cls = 0; cc = tid / 3;        ii = tid % 3;        hoff = 256 + tid; wB1 = 256 + cc; wB2 = 288 + cc; }
        else if (tid < 192) { int j = tid - 96; cls = 1; cc = j / 3; ii = j % 3; hoff = 352 + j;   wB1 = 320 + cc; wB2 = 352 + cc; }
        else                { int j = tid - 192; cls = 2; cc = j / 5;            hoff = 448 + j;   wB1 = 384 + cc; }
        ia = (ii + 1) % 3; ib = (ii + 2) % 3;

        const bool hasC = tid < 16;
        const int jC = 64 + tid;          // l2 channel slot 64..79
        const int hoffC = 448 + jC;       // feature offset 512..527
        const int wC = 384 + jC / 5;

        float accA = 0.f, accB = 0.f, accC = 0.f;
        for (int e = 0; e < ETM; ++e) {
            const int src = srcl[e];
            const float* hs = hcur + (size_t)src * FEAT;
            accA = fmaf(wl[e * WLP + tid], hs[tid], accA);
            float m;
            if (cls == 0) {
                float wv1 = wl[e * WLP + wB1], wsv = wl[e * WLP + wB2];
                m = wv1 * hs[hoff] + wsv * sv[(size_t)src * VDIM + cc] * y1l[e][ii];
            } else if (cls == 1) {
                float wv2 = wl[e * WLP + wB1], wcx = wl[e * WLP + wB2];
                float va = hs[256 + cc * 3 + ia], vb = hs[256 + cc * 3 + ib];
                m = wv2 * hs[hoff] + wcx * (va * y1l[e][ib] - vb * y1l[e][ia]);
            } else {
                m = wl[e * WLP + wB1] * hs[hoff];
            }
            accB += m;
            if (hasC) accC = fmaf(wl[e * WLP + wC], hs[hoffC], accC);

            bool fl = (e == ETM - 1) || (dstl[e + 1] != dstl[e]);
            if (fl) {
                int d = dstl[e];
                atomicAdd(&agg[(size_t)d * FEAT + tid], accA);
                atomicAdd(&agg[(size_t)d * FEAT + 256 + tid], accB);
                if (hasC) atomicAdd(&agg[(size_t)d * FEAT + hoffC], accC);
                accA = 0.f; accB = 0.f; accC = 0.f;
            }
        }
    }
}

// ================================================================ node kernel
__device__ __forceinline__ float block_reduce_sum(float v, float* red, int tid) {
    #pragma unroll
    for (int off = 32; off > 0; off >>= 1) v += __shfl_down(v, off, 64);
    if ((tid & 63) == 0) red[tid >> 6] = v;
    __syncthreads();
    float s = red[0] + red[1] + red[2] + red[3];
    __syncthreads();
    return s;
}

__global__ __launch_bounds__(256) void node_kernel(
    const float* __restrict__ hcur, const float* __restrict__ t_emb,
    const float* __restrict__ agg,
    const float* __restrict__ proj_s, const float* __restrict__ proj_v1,
    const float* __restrict__ proj_v2, const float* __restrict__ proj_l2,
    const float* __restrict__ adaW, const float* __restrict__ adab,
    float* __restrict__ hnext)
{
    const int n = blockIdx.x;
    const int tid = threadIdx.x;
    __shared__ float a_s[SDIM];
    __shared__ float te[TDIM];
    __shared__ float ada[ADA];
    __shared__ float av[272];
    __shared__ float vbuf[272];
    __shared__ float red[8];

    a_s[tid] = agg[(size_t)n * FEAT + tid] * DEG_INV;
    if (tid < TDIM) te[tid] = t_emb[(size_t)n * TDIM + tid];
    for (int i = tid; i < 272; i += 256)
        av[i] = agg[(size_t)n * FEAT + 256 + i] * DEG_INV;
    __syncthreads();

    for (int r = 0; r < 3; ++r) {
        int col = r * 256 + tid;
        if (col < ADA) {
            float acc = adab[col];
            for (int k = 0; k < TDIM; ++k) acc = fmaf(te[k], adaW[(size_t)k * ADA + col], acc);
            ada[col] = acc;
        }
    }

    float acc = 0.f;
    for (int k = 0; k < SDIM; ++k) acc = fmaf(a_s[k], proj_s[(size_t)k * SDIM + tid], acc);
    float us = acc / (1.f + expf(-acc));
    float sn = hcur[(size_t)n * FEAT + tid] + us;

    if (tid < 96) {
        int d = tid / 3, i = tid - d * 3;
        float a = 0.f;
        #pragma unroll
        for (int c = 0; c < VDIM; ++c) a = fmaf(av[c*3 + i], proj_v1[c * VDIM + d], a);
        vbuf[tid] = hcur[(size_t)n * FEAT + SDIM + tid] + a;
    } else if (tid < 192) {
        int t2 = tid - 96;
        int d = t2 / 3, i = t2 - d * 3;
        float a = 0.f;
        #pragma unroll
        for (int c = 0; c < VDIM; ++c) a = fmaf(av[96 + c*3 + i], proj_v2[c * VDIM + d], a);
        vbuf[tid] = hcur[(size_t)n * FEAT + SDIM + 3*VDIM + t2] + a;
    }
    if (tid < 80) {
        int d = tid / 5, i = tid - d * 5;
        float a = 0.f;
        #pragma unroll
        for (int c = 0; c < L2DIM; ++c) a = fmaf(av[192 + c*5 + i], proj_l2[c * L2DIM + d], a);
        vbuf[192 + tid] = hcur[(size_t)n * FEAT + SDIM + 6*VDIM + tid] + a;
    }
    __syncthreads();

    float ssum = block_reduce_sum(sn, red, tid);
    float ssq  = block_reduce_sum(sn * sn, red, tid);
    float mu = ssum * (1.f / SDIM);
    float var = ssq * (1.f / SDIM) - mu * mu;
    float rstd = rsqrtf(var + 1e-5f);
    hnext[(size_t)n * FEAT + tid] = (sn - mu) * rstd * (1.f + ada[tid]) + ada[SDIM + tid];

    float q1 = (tid < 96) ? vbuf[tid] * vbuf[tid] : 0.f;
    float S1 = block_reduce_sum(q1, red, tid);
    float q2 = (tid >= 96 && tid < 192) ? vbuf[tid] * vbuf[tid] : 0.f;
    float S2 = block_reduce_sum(q2, red, tid);
    float q3 = (tid < 80) ? vbuf[192 + tid] * vbuf[192 + tid] : 0.f;
    float S3 = block_reduce_sum(q3, red, tid);

    float r1 = rsqrtf(S1 * (1.f / VDIM) + 1e-5f);
    float r2 = rsqrtf(S2 * (1.f / VDIM) + 1e-5f);
    float r3 = rsqrtf(S3 * (1.f / L2DIM) + 1e-5f);

    if (tid < 96) {
        int d = tid / 3;
        hnext[(size_t)n * FEAT + SDIM + tid] = vbuf[tid] * r1 * (1.f + ada[2*SDIM + d]);
    } else if (tid < 192) {
        int t2 = tid - 96;
        int d = t2 / 3;
        hnext[(size_t)n * FEAT + SDIM + 3*VDIM + t2] = vbuf[tid] * r2 * (1.f + ada[2*SDIM + VDIM + d]);
    }
    if (tid < 80) {
        int d = tid / 5;
        hnext[(size_t)n * FEAT + SDIM + 6*VDIM + tid] = vbuf[192 + tid] * r3 * (1.f + ada[2*SDIM + 2*VDIM + d]);
    }
}

// ================================================================ launch
extern "C" void kernel_launch(void* const* d_in, const int* in_sizes, int n_in,
                              void* d_out, int out_size, void* d_ws, size_t ws_size,
                              hipStream_t stream) {
    const float* h_in   = (const float*)d_in[0];
    const float* coords = (const float*)d_in[1];
    const float* erd    = (const float*)d_in[2];
    const float* t_emb  = (const float*)d_in[3];
    const float* etype_emb   = (const float*)d_in[4];
    const float* btype_emb   = (const float*)d_in[5];
    const float* bconj_emb   = (const float*)d_in[6];
    const float* bring_emb   = (const float*)d_in[7];
    const float* bstereo_emb = (const float*)d_in[8];
    const float* refW   = (const float*)d_in[9];
    const float* refb   = (const float*)d_in[10];
    const float* edgeW  = (const float*)d_in[11];
    const float* edgeb  = (const float*)d_in[12];
    const float* svW    = (const float*)d_in[13];
    const float* proj_s = (const float*)d_in[14];
    const float* proj_v1= (const float*)d_in[15];
    const float* proj_v2= (const float*)d_in[16];
    const float* proj_l2= (const float*)d_in[17];
    const float* adaW   = (const float*)d_in[18];
    const float* adab   = (const float*)d_in[19];
    const int* eidx     = (const int*)d_in[20];
    const int* etype    = (const int*)d_in[21];
    const int* ebt      = (const int*)d_in[22];
    const int* ebc      = (const int*)d_in[23];
    const int* ebr      = (const int*)d_in[24];
    const int* ebs      = (const int*)d_in[25];

    float* ws_f    = (float*)d_ws;
    float* sv      = ws_f;                            // N*32
    float* agg     = sv + (size_t)NN * VDIM;          // N*528
    float* h1      = agg + (size_t)NN * FEAT;         // N*528
    float* srcdst  = h1 + (size_t)NN * FEAT;          // N*800
    int*   cnt     = (int*)(srcdst + (size_t)NN * 800);   // N
    int*   cursor  = cnt + NN;                        // N
    int*   perm    = cursor + NN;                     // E
    unsigned short* Wt1 = (unsigned short*)(perm + NE);   // 400*64
    unsigned short* Bn  = Wt1 + (size_t)WOUT * 64;        // 800*384

    // ---- sort edges by dst (once; reused by both layers)
    hipMemsetAsync(cnt, 0, NN * sizeof(int), stream);
    hist_kernel<<<(NE + 255) / 256, 256, 0, stream>>>(eidx, cnt);
    scan_kernel<<<1, 1024, 0, stream>>>(cnt, cursor);
    scatter_kernel<<<(NE + 255) / 256, 256, 0, stream>>>(eidx, cursor, perm);

    for (int l = 0; l < 2; ++l) {
        const float* hcur = (l == 0) ? h_in : h1;
        float* hnext      = (l == 0) ? h1 : (float*)d_out;
        const float* W    = edgeW + (size_t)l * 700 * WOUT;

        hipMemsetAsync(agg, 0, (size_t)NN * FEAT * sizeof(float), stream);
        wt1_kernel<<<(WOUT * 64 + 255) / 256, 256, 0, stream>>>(W, Wt1);
        bnode_kernel<<<dim3(2, 800), 256, 0, stream>>>(W, Bn);
        sv_kernel<<<(NN * VDIM + 255) / 256, 256, 0, stream>>>(hcur, svW + l * SDIM * VDIM, sv);
        nodeproj_kernel<<<(NN + 31) / 32, 256, 0, stream>>>(hcur, t_emb, Bn, edgeb + l * WOUT, srcdst);
        edge_kernel<<<NE / ETM, 256, 0, stream>>>(
            hcur, coords, erd, sv, Wt1, srcdst, perm,
            eidx, etype, ebt, ebc, ebr, ebs,
            etype_emb + l * 144, btype_emb + l * 48, bconj_emb + l * 12,
            bring_emb + l * 12, bstereo_emb + l * 20,
            refW + l * 24, refb + l * 8,
            agg);
        node_kernel<<<NN, 256, 0, stream>>>(
            hcur, t_emb, agg,
            proj_s + (size_t)l * SDIM * SDIM, proj_v1 + l * VDIM * VDIM,
            proj_v2 + l * VDIM * VDIM, proj_l2 + l * L2DIM * L2DIM,
            adaW + (size_t)l * TDIM * ADA, adab + l * ADA,
            hnext);
    }
}

// Round 5
// 998.262 us; speedup vs baseline: 4.4540x; 1.7085x over previous
//
#include <hip/hip_runtime.h>
#include <math.h>

#define NN 10000
#define NE 160000
#define SDIM 256
#define VDIM 32
#define L2DIM 16
#define TDIM 128
#define FEAT 528      // S + 3V + 3V + 5*L2
#define WOUT 400      // S + 4V + L2
#define ADA 592       // 2S+2V+L2
#define DEG_INV 0.25f

#define ETM 16        // edges per block
#define WLP 404       // w LDS stride (f32)
#define AP1 72        // misc A stride (bf16)
#define AP2 392       // nodeproj A stride (bf16)

typedef short bf16x8 __attribute__((ext_vector_type(8)));
typedef float f32x4 __attribute__((ext_vector_type(4)));

__device__ __forceinline__ unsigned short f2bf(float f) {
    unsigned int u = __float_as_uint(f);
    u += 0x7fffu + ((u >> 16) & 1u);      // round-to-nearest-even
    return (unsigned short)(u >> 16);
}
__device__ __forceinline__ float bf2f(unsigned short b) {
    return __uint_as_float(((unsigned int)b) << 16);
}

// ================================================================ sort by dst
__global__ __launch_bounds__(256) void hist_kernel(const int* __restrict__ eidx,
                                                   int* __restrict__ cnt) {
    int e = blockIdx.x * 256 + threadIdx.x;
    if (e < NE) atomicAdd(&cnt[eidx[NE + e]], 1);
}

__global__ __launch_bounds__(1024) void scan_kernel(const int* __restrict__ cnt,
                                                    int* __restrict__ cursor) {
    __shared__ int sc[1024];
    int tid = threadIdx.x;
    int base = tid * 10;
    int loc[10];
    int s = 0;
    if (base < NN) {
        #pragma unroll
        for (int j = 0; j < 10; ++j) { loc[j] = cnt[base + j]; s += loc[j]; }
    }
    sc[tid] = s;
    __syncthreads();
    for (int off = 1; off < 1024; off <<= 1) {
        int v = sc[tid];
        int add = (tid >= off) ? sc[tid - off] : 0;
        __syncthreads();
        sc[tid] = v + add;
        __syncthreads();
    }
    int run = sc[tid] - s;   // exclusive prefix
    if (base < NN) {
        #pragma unroll
        for (int j = 0; j < 10; ++j) { cursor[base + j] = run; run += loc[j]; }
    }
}

__global__ __launch_bounds__(256) void scatter_kernel(const int* __restrict__ eidx,
                                                      int* __restrict__ cursor,
                                                      int* __restrict__ perm) {
    int e = blockIdx.x * 256 + threadIdx.x;
    if (e < NE) {
        int d = eidx[NE + e];
        int p = atomicAdd(&cursor[d], 1);
        perm[p] = e;
    }
}

// ================================================================ weight prep
__global__ __launch_bounds__(256) void wt1_kernel(const float* __restrict__ W,
                                                  unsigned short* __restrict__ Wt1) {
    int idx = blockIdx.x * 256 + threadIdx.x;      // 400*64 items
    if (idx >= WOUT * 64) return;
    int c = idx >> 6, k = idx & 63;
    float v = (k < 60) ? W[(size_t)k * WOUT + c] : 0.f;
    Wt1[idx] = f2bf(v);
}

__global__ __launch_bounds__(256) void bnode_kernel(const float* __restrict__ W,
                                                    unsigned short* __restrict__ Bn) {
    int k = blockIdx.x * 256 + threadIdx.x;
    if (k >= 384) return;
    int c = blockIdx.y;
    float v;
    if (c < WOUT) v = (k < 256) ? W[(size_t)(60 + k) * WOUT + c] : 0.f;
    else {
        int c2 = c - WOUT;
        v = (k < 256) ? W[(size_t)(316 + k) * WOUT + c2]
                      : W[(size_t)(572 + (k - 256)) * WOUT + c2];
    }
    Bn[(size_t)c * 384 + k] = f2bf(v);
}

// Ba[c][k] = bf16(ada_W[k][c]), c<592, k<128
__global__ __launch_bounds__(256) void bada_kernel(const float* __restrict__ adaW,
                                                   unsigned short* __restrict__ Ba) {
    int idx = blockIdx.x * 256 + threadIdx.x;
    if (idx >= ADA * 128) return;
    int c = idx >> 7, k = idx & 127;
    Ba[idx] = f2bf(adaW[(size_t)k * ADA + c]);
}

// ================================================================ hb = bf16(h)
struct us4 { unsigned short x, y, z, w; };
__global__ __launch_bounds__(256) void hb_kernel(const float* __restrict__ h,
                                                 unsigned short* __restrict__ hb) {
    int i = blockIdx.x * 256 + threadIdx.x;
    if (i >= NN * FEAT / 4) return;
    float4 v = ((const float4*)h)[i];
    us4 o;
    o.x = f2bf(v.x); o.y = f2bf(v.y); o.z = f2bf(v.z); o.w = f2bf(v.w);
    ((us4*)hb)[i] = o;
}

// ================================================================ sv = s @ sv_W
__global__ __launch_bounds__(256) void sv_kernel(const float* __restrict__ hcur,
                                                 const float* __restrict__ svW,
                                                 float* __restrict__ sv) {
    int i = blockIdx.x * 256 + threadIdx.x;
    if (i >= NN * VDIM) return;
    int n = i >> 5, v = i & 31;
    const float* hs = hcur + (size_t)n * FEAT;
    float acc = 0.f;
    for (int k = 0; k < SDIM; ++k) acc = fmaf(hs[k], svW[k * VDIM + v], acc);
    sv[i] = acc;
}

// ================================================================ nodeproj: srcdst (bf16) + ada_buf (f32)
__global__ __launch_bounds__(256) void nodeproj_kernel(
    const unsigned short* __restrict__ hb, const float* __restrict__ t_emb,
    const unsigned short* __restrict__ Bn, const unsigned short* __restrict__ Ba,
    const float* __restrict__ edge_b, const float* __restrict__ adab,
    unsigned short* __restrict__ srcdst, float* __restrict__ ada_out)
{
    __shared__ unsigned short As2[32 * AP2];
    const int tid = threadIdx.x;
    const int n0 = blockIdx.x * 32;

    for (int e = 0; e < 32; ++e) {
        int n = n0 + e;
        As2[e * AP2 + tid] = (n < NN) ? hb[(size_t)n * FEAT + tid] : 0;
        if (tid < 128) {
            float v1 = (n < NN) ? t_emb[(size_t)n * TDIM + tid] : 0.f;
            As2[e * AP2 + 256 + tid] = f2bf(v1);
        }
    }
    __syncthreads();

    const int wid = tid >> 6, lane = tid & 63;
    const int lr = lane & 15, lkb = (lane >> 4) << 3;
    const int rbase = (lane >> 4) << 2;

    // ---- main: 50 tiles, K=384
    {
        const int nt0 = wid * 13;
        f32x4 acc[2][13];
        #pragma unroll
        for (int m = 0; m < 2; ++m)
            #pragma unroll
            for (int t = 0; t < 13; ++t) acc[m][t] = (f32x4){0.f, 0.f, 0.f, 0.f};

        for (int ks = 0; ks < 12; ++ks) {
            int kb = ks * 32 + lkb;
            bf16x8 a0 = *(const bf16x8*)&As2[lr * AP2 + kb];
            bf16x8 a1 = *(const bf16x8*)&As2[(16 + lr) * AP2 + kb];
            #pragma unroll
            for (int t = 0; t < 13; ++t) {
                int tile = nt0 + t;
                if (tile < 50) {
                    bf16x8 b = *(const bf16x8*)&Bn[(size_t)(tile * 16 + lr) * 384 + kb];
                    acc[0][t] = __builtin_amdgcn_mfma_f32_16x16x32_bf16(a0, b, acc[0][t], 0, 0, 0);
                    acc[1][t] = __builtin_amdgcn_mfma_f32_16x16x32_bf16(a1, b, acc[1][t], 0, 0, 0);
                }
            }
        }
        #pragma unroll
        for (int t = 0; t < 13; ++t) {
            int tile = nt0 + t;
            if (tile < 50) {
                int col = tile * 16 + lr;
                float badd = (col >= WOUT) ? edge_b[col - WOUT] : 0.f;
                #pragma unroll
                for (int m = 0; m < 2; ++m) {
                    #pragma unroll
                    for (int r = 0; r < 4; ++r) {
                        int n = n0 + m * 16 + rbase + r;
                        if (n < NN) srcdst[(size_t)n * 800 + col] = f2bf(acc[m][t][r] + badd);
                    }
                }
            }
        }
    }

    // ---- ada: 37 tiles, K=128 (As2 cols 256..384)
    {
        const int nt0a = wid * 9;
        f32x4 acc2[2][10];
        #pragma unroll
        for (int m = 0; m < 2; ++m)
            #pragma unroll
            for (int t = 0; t < 10; ++t) acc2[m][t] = (f32x4){0.f, 0.f, 0.f, 0.f};

        for (int ks = 0; ks < 4; ++ks) {
            int kin = ks * 32 + lkb;
            bf16x8 a0 = *(const bf16x8*)&As2[lr * AP2 + 256 + kin];
            bf16x8 a1 = *(const bf16x8*)&As2[(16 + lr) * AP2 + 256 + kin];
            #pragma unroll
            for (int t = 0; t < 10; ++t) {
                int tile = nt0a + t;
                if (tile < 37) {
                    bf16x8 b = *(const bf16x8*)&Ba[(size_t)(tile * 16 + lr) * 128 + kin];
                    acc2[0][t] = __builtin_amdgcn_mfma_f32_16x16x32_bf16(a0, b, acc2[0][t], 0, 0, 0);
                    acc2[1][t] = __builtin_amdgcn_mfma_f32_16x16x32_bf16(a1, b, acc2[1][t], 0, 0, 0);
                }
            }
        }
        #pragma unroll
        for (int t = 0; t < 10; ++t) {
            int tile = nt0a + t;
            if (tile < 37) {
                int col = tile * 16 + lr;
                float badd = adab[col];
                #pragma unroll
                for (int m = 0; m < 2; ++m) {
                    #pragma unroll
                    for (int r = 0; r < 4; ++r) {
                        int n = n0 + m * 16 + rbase + r;
                        if (n < NN) ada_out[(size_t)n * ADA + col] = acc2[m][t][r] + badd;
                    }
                }
            }
        }
    }
}

// ================================================================ edge kernel
__global__ __launch_bounds__(256) void edge_kernel(
    const unsigned short* __restrict__ hb, const float* __restrict__ coords,
    const float* __restrict__ erd, const float* __restrict__ sv,
    const unsigned short* __restrict__ Wt1, const unsigned short* __restrict__ srcdst,
    const int* __restrict__ perm, const int* __restrict__ eidx,
    const int* __restrict__ etype, const int* __restrict__ ebt,
    const int* __restrict__ ebc, const int* __restrict__ ebr,
    const int* __restrict__ ebs,
    const float* __restrict__ etype_emb, const float* __restrict__ btype_emb,
    const float* __restrict__ bconj_emb, const float* __restrict__ bring_emb,
    const float* __restrict__ bstereo_emb,
    const float* __restrict__ refW, const float* __restrict__ refb,
    float* __restrict__ agg)
{
    __shared__ float wl[ETM * WLP];              // 25.9 KB
    __shared__ unsigned short As[ETM * AP1];     // 2.3 KB
    __shared__ int srcl[ETM], dstl[ETM];
    __shared__ int itype[ETM], ibt[ETM], ibc[ETM], ibr[ETM], ibs[ETM];
    __shared__ float distl[ETM], erdl[ETM], y1l[ETM][3];

    const int tid = threadIdx.x;
    const int e0 = blockIdx.x * ETM;

    if (tid < ETM) {
        int ge = perm[e0 + tid];
        int s = eidx[ge], d = eidx[NE + ge];
        srcl[tid] = s; dstl[tid] = d;
        itype[tid] = etype[ge]; ibt[tid] = ebt[ge]; ibc[tid] = ebc[ge];
        ibr[tid] = ebr[ge]; ibs[tid] = ebs[ge];
        float dx = coords[d*3+0] - coords[s*3+0];
        float dy = coords[d*3+1] - coords[s*3+1];
        float dz = coords[d*3+2] - coords[s*3+2];
        float dist = sqrtf(dx*dx + dy*dy + dz*dz);
        distl[tid] = dist;
        float inv = 1.f / (dist + 1e-8f);
        y1l[tid][0] = dx * inv; y1l[tid][1] = dy * inv; y1l[tid][2] = dz * inv;
        erdl[tid] = erd[ge];
    }
    __syncthreads();

    // ---- stage misc features (k<60, padded to 64) as bf16
    {
        const int k = tid & 63;
        const int ebase = tid >> 6;
        #pragma unroll
        for (int it = 0; it < 4; ++it) {
            int e = it * 4 + ebase;
            float de = distl[e];
            float v;
            if (k >= 60) v = 0.f;
            else if (k < 16) { float x = (de - (float)k * (10.f/15.f)) * 1.6f; v = expf(-x*x); }
            else if (k < 32) v = etype_emb[itype[e]*16 + (k-16)];
            else if (k < 40) v = btype_emb[ibt[e]*8 + (k-32)];
            else if (k < 44) v = bconj_emb[ibc[e]*4 + (k-40)];
            else if (k < 48) v = bring_emb[ibr[e]*4 + (k-44)];
            else if (k < 52) v = bstereo_emb[ibs[e]*4 + (k-48)];
            else {
                int j = k - 52;
                float dd = de - erdl[e];
                float hr = erdl[e] > 0.f ? 1.f : 0.f;
                v = fabsf(dd)*refW[j] + dd*refW[8+j] + hr*refW[16+j] + refb[j];
            }
            As[e * AP1 + k] = f2bf(v);
        }
    }
    __syncthreads();

    // ---- tiny MFMA GEMM (misc) + fused srcdst gather-add, all in epilogue
    const int wid = tid >> 6, lane = tid & 63;
    const int lr = lane & 15, lkb = (lane >> 4) << 3;
    const int nt0 = wid * 6;                  // 25 tiles / 4 waves, 7 each (overlap dup)
    {
        f32x4 acc[7];
        #pragma unroll
        for (int t = 0; t < 7; ++t) acc[t] = (f32x4){0.f, 0.f, 0.f, 0.f};

        #pragma unroll
        for (int ks = 0; ks < 2; ++ks) {
            int kb = ks * 32 + lkb;
            bf16x8 a0 = *(const bf16x8*)&As[lr * AP1 + kb];
            #pragma unroll
            for (int t = 0; t < 7; ++t) {
                bf16x8 b = *(const bf16x8*)&Wt1[(size_t)((nt0 + t) * 16 + lr) * 64 + kb];
                acc[t] = __builtin_amdgcn_mfma_f32_16x16x32_bf16(a0, b, acc[t], 0, 0, 0);
            }
        }
        const int rbase = (lane >> 4) << 2;
        int se[4], de_[4];
        #pragma unroll
        for (int r = 0; r < 4; ++r) { se[r] = srcl[rbase + r]; de_[r] = dstl[rbase + r]; }
        #pragma unroll
        for (int t = 0; t < 7; ++t) {
            const int col = (nt0 + t) * 16 + lr;
            #pragma unroll
            for (int r = 0; r < 4; ++r) {
                float add = bf2f(srcdst[(size_t)se[r] * 800 + col])
                          + bf2f(srcdst[(size_t)de_[r] * 800 + 400 + col]);
                wl[(rbase + r) * WLP + col] = acc[t][r] + add;
            }
        }
    }
    __syncthreads();

    // ---- messages with run-accumulation (edges sorted by dst)
    {
        int cls = 0, cc = 0, ii = 0, ia = 0, ib = 0, hoff = 0, wB1 = 0, wB2 = 0;
        if (tid < 96)       { cls = 0; cc = tid / 3;        ii = tid % 3;        hoff = 256 + tid; wB1 = 256 + cc; wB2 = 288 + cc; }
        else if (tid < 192) { int j = tid - 96; cls = 1; cc = j / 3; ii = j % 3; hoff = 352 + j;   wB1 = 320 + cc; wB2 = 352 + cc; }
        else                { int j = tid - 192; cls = 2; cc = j / 5;            hoff = 448 + j;   wB1 = 384 + cc; }
        ia = (ii + 1) % 3; ib = (ii + 2) % 3;

        const bool hasC = tid < 16;
        const int jC = 64 + tid;          // l2 channel slot 64..79
        const int hoffC = 448 + jC;       // feature offset 512..527
        const int wC = 384 + jC / 5;

        float accA = 0.f, accB = 0.f, accC = 0.f;
        for (int e = 0; e < ETM; ++e) {
            const int src = srcl[e];
            const unsigned short* hs = hb + (size_t)src * FEAT;
            accA = fmaf(wl[e * WLP + tid], bf2f(hs[tid]), accA);
            float m;
            if (cls == 0) {
                float wv1 = wl[e * WLP + wB1], wsv = wl[e * WLP + wB2];
                m = wv1 * bf2f(hs[hoff]) + wsv * sv[(size_t)src * VDIM + cc] * y1l[e][ii];
            } else if (cls == 1) {
                float wv2 = wl[e * WLP + wB1], wcx = wl[e * WLP + wB2];
                float va = bf2f(hs[256 + cc * 3 + ia]), vb = bf2f(hs[256 + cc * 3 + ib]);
                m = wv2 * bf2f(hs[hoff]) + wcx * (va * y1l[e][ib] - vb * y1l[e][ia]);
            } else {
                m = wl[e * WLP + wB1] * bf2f(hs[hoff]);
            }
            accB += m;
            if (hasC) accC = fmaf(wl[e * WLP + wC], bf2f(hs[hoffC]), accC);

            bool fl = (e == ETM - 1) || (dstl[e + 1] != dstl[e]);
            if (fl) {
                int d = dstl[e];
                atomicAdd(&agg[(size_t)d * FEAT + tid], accA);
                atomicAdd(&agg[(size_t)d * FEAT + 256 + tid], accB);
                if (hasC) atomicAdd(&agg[(size_t)d * FEAT + hoffC], accC);
                accA = 0.f; accB = 0.f; accC = 0.f;
            }
        }
    }
}

// ================================================================ node kernel
__device__ __forceinline__ float block_reduce_sum(float v, float* red, int tid) {
    #pragma unroll
    for (int off = 32; off > 0; off >>= 1) v += __shfl_down(v, off, 64);
    if ((tid & 63) == 0) red[tid >> 6] = v;
    __syncthreads();
    float s = red[0] + red[1] + red[2] + red[3];
    __syncthreads();
    return s;
}

__global__ __launch_bounds__(256) void node_kernel(
    const float* __restrict__ hcur, const float* __restrict__ ada_buf,
    const float* __restrict__ agg,
    const float* __restrict__ proj_s, const float* __restrict__ proj_v1,
    const float* __restrict__ proj_v2, const float* __restrict__ proj_l2,
    float* __restrict__ hnext)
{
    const int n = blockIdx.x;
    const int tid = threadIdx.x;
    __shared__ float a_s[SDIM];
    __shared__ float ada[ADA];
    __shared__ float av[272];
    __shared__ float vbuf[272];
    __shared__ float red[8];

    a_s[tid] = agg[(size_t)n * FEAT + tid] * DEG_INV;
    for (int i = tid; i < 272; i += 256)
        av[i] = agg[(size_t)n * FEAT + 256 + i] * DEG_INV;
    for (int r = 0; r < 3; ++r) {
        int col = r * 256 + tid;
        if (col < ADA) ada[col] = ada_buf[(size_t)n * ADA + col];
    }
    __syncthreads();

    float acc = 0.f;
    for (int k = 0; k < SDIM; ++k) acc = fmaf(a_s[k], proj_s[(size_t)k * SDIM + tid], acc);
    float us = acc / (1.f + expf(-acc));
    float sn = hcur[(size_t)n * FEAT + tid] + us;

    if (tid < 96) {
        int d = tid / 3, i = tid - d * 3;
        float a = 0.f;
        #pragma unroll
        for (int c = 0; c < VDIM; ++c) a = fmaf(av[c*3 + i], proj_v1[c * VDIM + d], a);
        vbuf[tid] = hcur[(size_t)n * FEAT + SDIM + tid] + a;
    } else if (tid < 192) {
        int t2 = tid - 96;
        int d = t2 / 3, i = t2 - d * 3;
        float a = 0.f;
        #pragma unroll
        for (int c = 0; c < VDIM; ++c) a = fmaf(av[96 + c*3 + i], proj_v2[c * VDIM + d], a);
        vbuf[tid] = hcur[(size_t)n * FEAT + SDIM + 3*VDIM + t2] + a;
    }
    if (tid < 80) {
        int d = tid / 5, i = tid - d * 5;
        float a = 0.f;
        #pragma unroll
        for (int c = 0; c < L2DIM; ++c) a = fmaf(av[192 + c*5 + i], proj_l2[c * L2DIM + d], a);
        vbuf[192 + tid] = hcur[(size_t)n * FEAT + SDIM + 6*VDIM + tid] + a;
    }
    __syncthreads();

    float ssum = block_reduce_sum(sn, red, tid);
    float ssq  = block_reduce_sum(sn * sn, red, tid);
    float mu = ssum * (1.f / SDIM);
    float var = ssq * (1.f / SDIM) - mu * mu;
    float rstd = rsqrtf(var + 1e-5f);
    hnext[(size_t)n * FEAT + tid] = (sn - mu) * rstd * (1.f + ada[tid]) + ada[SDIM + tid];

    float q1 = (tid < 96) ? vbuf[tid] * vbuf[tid] : 0.f;
    float S1 = block_reduce_sum(q1, red, tid);
    float q2 = (tid >= 96 && tid < 192) ? vbuf[tid] * vbuf[tid] : 0.f;
    float S2 = block_reduce_sum(q2, red, tid);
    float q3 = (tid < 80) ? vbuf[192 + tid] * vbuf[192 + tid] : 0.f;
    float S3 = block_reduce_sum(q3, red, tid);

    float r1 = rsqrtf(S1 * (1.f / VDIM) + 1e-5f);
    float r2 = rsqrtf(S2 * (1.f / VDIM) + 1e-5f);
    float r3 = rsqrtf(S3 * (1.f / L2DIM) + 1e-5f);

    if (tid < 96) {
        int d = tid / 3;
        hnext[(size_t)n * FEAT + SDIM + tid] = vbuf[tid] * r1 * (1.f + ada[2*SDIM + d]);
    } else if (tid < 192) {
        int t2 = tid - 96;
        int d = t2 / 3;
        hnext[(size_t)n * FEAT + SDIM + 3*VDIM + t2] = vbuf[tid] * r2 * (1.f + ada[2*SDIM + VDIM + d]);
    }
    if (tid < 80) {
        int d = tid / 5;
        hnext[(size_t)n * FEAT + SDIM + 6*VDIM + tid] = vbuf[192 + tid] * r3 * (1.f + ada[2*SDIM + 2*VDIM + d]);
    }
}

// ================================================================ launch
extern "C" void kernel_launch(void* const* d_in, const int* in_sizes, int n_in,
                              void* d_out, int out_size, void* d_ws, size_t ws_size,
                              hipStream_t stream) {
    const float* h_in   = (const float*)d_in[0];
    const float* coords = (const float*)d_in[1];
    const float* erd    = (const float*)d_in[2];
    const float* t_emb  = (const float*)d_in[3];
    const float* etype_emb   = (const float*)d_in[4];
    const float* btype_emb   = (const float*)d_in[5];
    const float* bconj_emb   = (const float*)d_in[6];
    const float* bring_emb   = (const float*)d_in[7];
    const float* bstereo_emb = (const float*)d_in[8];
    const float* refW   = (const float*)d_in[9];
    const float* refb   = (const float*)d_in[10];
    const float* edgeW  = (const float*)d_in[11];
    const float* edgeb  = (const float*)d_in[12];
    const float* svW    = (const float*)d_in[13];
    const float* proj_s = (const float*)d_in[14];
    const float* proj_v1= (const float*)d_in[15];
    const float* proj_v2= (const float*)d_in[16];
    const float* proj_l2= (const float*)d_in[17];
    const float* adaW   = (const float*)d_in[18];
    const float* adab   = (const float*)d_in[19];
    const int* eidx     = (const int*)d_in[20];
    const int* etype    = (const int*)d_in[21];
    const int* ebt      = (const int*)d_in[22];
    const int* ebc      = (const int*)d_in[23];
    const int* ebr      = (const int*)d_in[24];
    const int* ebs      = (const int*)d_in[25];

    float* ws_f     = (float*)d_ws;
    float* sv       = ws_f;                           // N*32
    float* agg      = sv + (size_t)NN * VDIM;         // N*528
    float* h1       = agg + (size_t)NN * FEAT;        // N*528
    float* ada_buf  = h1 + (size_t)NN * FEAT;         // N*592
    unsigned short* srcdst = (unsigned short*)(ada_buf + (size_t)NN * ADA);  // N*800
    unsigned short* hb     = srcdst + (size_t)NN * 800;                      // N*528
    unsigned short* Wt1    = hb + (size_t)NN * FEAT;                         // 400*64
    unsigned short* Bn     = Wt1 + (size_t)WOUT * 64;                        // 800*384
    unsigned short* Ba     = Bn + (size_t)800 * 384;                         // 592*128
    int* cnt    = (int*)(Ba + (size_t)ADA * 128);     // N
    int* cursor = cnt + NN;                           // N
    int* perm   = cursor + NN;                        // E

    // ---- sort edges by dst (once; reused by both layers)
    hipMemsetAsync(cnt, 0, NN * sizeof(int), stream);
    hist_kernel<<<(NE + 255) / 256, 256, 0, stream>>>(eidx, cnt);
    scan_kernel<<<1, 1024, 0, stream>>>(cnt, cursor);
    scatter_kernel<<<(NE + 255) / 256, 256, 0, stream>>>(eidx, cursor, perm);

    for (int l = 0; l < 2; ++l) {
        const float* hcur = (l == 0) ? h_in : h1;
        float* hnext      = (l == 0) ? h1 : (float*)d_out;
        const float* W    = edgeW + (size_t)l * 700 * WOUT;

        hipMemsetAsync(agg, 0, (size_t)NN * FEAT * sizeof(float), stream);
        wt1_kernel<<<(WOUT * 64 + 255) / 256, 256, 0, stream>>>(W, Wt1);
        bnode_kernel<<<dim3(2, 800), 256, 0, stream>>>(W, Bn);
        bada_kernel<<<(ADA * 128 + 255) / 256, 256, 0, stream>>>(adaW + (size_t)l * TDIM * ADA, Ba);
        hb_kernel<<<(NN * FEAT / 4 + 255) / 256, 256, 0, stream>>>(hcur, hb);
        sv_kernel<<<(NN * VDIM + 255) / 256, 256, 0, stream>>>(hcur, svW + l * SDIM * VDIM, sv);
        nodeproj_kernel<<<(NN + 31) / 32, 256, 0, stream>>>(
            hb, t_emb, Bn, Ba, edgeb + l * WOUT, adab + l * ADA, srcdst, ada_buf);
        edge_kernel<<<NE / ETM, 256, 0, stream>>>(
            hb, coords, erd, sv, Wt1, srcdst, perm,
            eidx, etype, ebt, ebc, ebr, ebs,
            etype_emb + l * 144, btype_emb + l * 48, bconj_emb + l * 12,
            bring_emb + l * 12, bstereo_emb + l * 20,
            refW + l * 24, refb + l * 8,
            agg);
        node_kernel<<<NN, 256, 0, stream>>>(
            hcur, ada_buf, agg,
            proj_s + (size_t)l * SDIM * SDIM, proj_v1 + l * VDIM * VDIM,
            proj_v2 + l * VDIM * VDIM, proj_l2 + l * L2DIM * L2DIM,
            hnext);
    }
}

// Round 6
// 869.682 us; speedup vs baseline: 5.1125x; 1.1478x over previous
//
#include <hip/hip_runtime.h>
#include <math.h>

#define NN 10000
#define NE 160000
#define SDIM 256
#define VDIM 32
#define L2DIM 16
#define TDIM 128
#define FEAT 528      // S + 3V + 3V + 5*L2
#define WOUT 400      // S + 4V + L2
#define ADA 592       // 2S+2V+L2
#define DEG_INV 0.25f

#define ETM 16        // edges per block
#define WLP 404       // w LDS stride (bf16 elems)
#define AP1 72        // misc A stride (bf16)
#define AP2 392       // nodeproj A stride (bf16)
#define AP3 264       // proj kernel A stride (bf16)

typedef short bf16x8 __attribute__((ext_vector_type(8)));
typedef float f32x4 __attribute__((ext_vector_type(4)));

__device__ __forceinline__ unsigned short f2bf(float f) {
    unsigned int u = __float_as_uint(f);
    u += 0x7fffu + ((u >> 16) & 1u);      // round-to-nearest-even
    return (unsigned short)(u >> 16);
}
__device__ __forceinline__ float bf2f(unsigned short b) {
    return __uint_as_float(((unsigned int)b) << 16);
}

// ================================================================ sort by dst
__global__ __launch_bounds__(256) void hist_kernel(const int* __restrict__ eidx,
                                                   int* __restrict__ cnt) {
    int e = blockIdx.x * 256 + threadIdx.x;
    if (e < NE) atomicAdd(&cnt[eidx[NE + e]], 1);
}

__global__ __launch_bounds__(1024) void scan_kernel(const int* __restrict__ cnt,
                                                    int* __restrict__ cursor) {
    __shared__ int sc[1024];
    int tid = threadIdx.x;
    int base = tid * 10;
    int loc[10];
    int s = 0;
    if (base < NN) {
        #pragma unroll
        for (int j = 0; j < 10; ++j) { loc[j] = cnt[base + j]; s += loc[j]; }
    }
    sc[tid] = s;
    __syncthreads();
    for (int off = 1; off < 1024; off <<= 1) {
        int v = sc[tid];
        int add = (tid >= off) ? sc[tid - off] : 0;
        __syncthreads();
        sc[tid] = v + add;
        __syncthreads();
    }
    int run = sc[tid] - s;   // exclusive prefix
    if (base < NN) {
        #pragma unroll
        for (int j = 0; j < 10; ++j) { cursor[base + j] = run; run += loc[j]; }
    }
}

__global__ __launch_bounds__(256) void scatter_kernel(const int* __restrict__ eidx,
                                                      int* __restrict__ cursor,
                                                      int* __restrict__ perm) {
    int e = blockIdx.x * 256 + threadIdx.x;
    if (e < NE) {
        int d = eidx[NE + e];
        int p = atomicAdd(&cursor[d], 1);
        perm[p] = e;
    }
}

// ================================================================ fused weight prep
// Wt1[400][64], Bn[800][384], Ba[592][128], Bsv[32][256], Ps[256][256]
#define O1 25600
#define O2 332800
#define O3 408576
#define O4 416768
#define O5 482304
__global__ __launch_bounds__(256) void prep_kernel(
    const float* __restrict__ W, const float* __restrict__ adaW,
    const float* __restrict__ svW, const float* __restrict__ projs,
    unsigned short* __restrict__ Wt1, unsigned short* __restrict__ Bn,
    unsigned short* __restrict__ Ba, unsigned short* __restrict__ Bsv,
    unsigned short* __restrict__ Ps)
{
    int idx = blockIdx.x * 256 + threadIdx.x;
    if (idx < O1) {
        int c = idx >> 6, k = idx & 63;
        float v = (k < 60) ? W[(size_t)k * WOUT + c] : 0.f;
        Wt1[idx] = f2bf(v);
    } else if (idx < O2) {
        int i = idx - O1;
        int c = i / 384, k = i - c * 384;
        float v;
        if (c < WOUT) v = (k < 256) ? W[(size_t)(60 + k) * WOUT + c] : 0.f;
        else {
            int c2 = c - WOUT;
            v = (k < 256) ? W[(size_t)(316 + k) * WOUT + c2]
                          : W[(size_t)(572 + (k - 256)) * WOUT + c2];
        }
        Bn[i] = f2bf(v);
    } else if (idx < O3) {
        int i = idx - O2;
        int c = i >> 7, k = i & 127;
        Ba[i] = f2bf(adaW[(size_t)k * ADA + c]);
    } else if (idx < O4) {
        int i = idx - O3;
        int c = i >> 8, k = i & 255;
        Bsv[i] = f2bf(svW[(size_t)k * VDIM + c]);
    } else if (idx < O5) {
        int i = idx - O4;
        int c = i >> 8, k = i & 255;
        Ps[i] = f2bf(projs[(size_t)k * SDIM + c]);
    }
}

// ================================================================ hb = bf16(h) (input layer only)
struct us4 { unsigned short x, y, z, w; };
__global__ __launch_bounds__(256) void hb_kernel(const float* __restrict__ h,
                                                 unsigned short* __restrict__ hb) {
    int i = blockIdx.x * 256 + threadIdx.x;
    if (i >= NN * FEAT / 4) return;
    float4 v = ((const float4*)h)[i];
    us4 o;
    o.x = f2bf(v.x); o.y = f2bf(v.y); o.z = f2bf(v.z); o.w = f2bf(v.w);
    ((us4*)hb)[i] = o;
}

// ================================================================ nodeproj: srcdst (bf16) + ada (f32) + sv (f32)
__global__ __launch_bounds__(256) void nodeproj_kernel(
    const unsigned short* __restrict__ hb, const float* __restrict__ t_emb,
    const unsigned short* __restrict__ Bn, const unsigned short* __restrict__ Ba,
    const unsigned short* __restrict__ Bsv,
    const float* __restrict__ edge_b, const float* __restrict__ adab,
    unsigned short* __restrict__ srcdst, float* __restrict__ ada_out,
    float* __restrict__ sv)
{
    __shared__ unsigned short As2[32 * AP2];
    const int tid = threadIdx.x;
    const int n0 = blockIdx.x * 32;

    for (int e = 0; e < 32; ++e) {
        int n = n0 + e;
        As2[e * AP2 + tid] = (n < NN) ? hb[(size_t)n * FEAT + tid] : 0;
        if (tid < 128) {
            float v1 = (n < NN) ? t_emb[(size_t)n * TDIM + tid] : 0.f;
            As2[e * AP2 + 256 + tid] = f2bf(v1);
        }
    }
    __syncthreads();

    const int wid = tid >> 6, lane = tid & 63;
    const int lr = lane & 15, lkb = (lane >> 4) << 3;
    const int rbase = (lane >> 4) << 2;

    // ---- main: 50 tiles, K=384
    {
        const int nt0 = wid * 13;
        f32x4 acc[2][13];
        #pragma unroll
        for (int m = 0; m < 2; ++m)
            #pragma unroll
            for (int t = 0; t < 13; ++t) acc[m][t] = (f32x4){0.f, 0.f, 0.f, 0.f};

        for (int ks = 0; ks < 12; ++ks) {
            int kb = ks * 32 + lkb;
            bf16x8 a0 = *(const bf16x8*)&As2[lr * AP2 + kb];
            bf16x8 a1 = *(const bf16x8*)&As2[(16 + lr) * AP2 + kb];
            #pragma unroll
            for (int t = 0; t < 13; ++t) {
                int tile = nt0 + t;
                if (tile < 50) {
                    bf16x8 b = *(const bf16x8*)&Bn[(size_t)(tile * 16 + lr) * 384 + kb];
                    acc[0][t] = __builtin_amdgcn_mfma_f32_16x16x32_bf16(a0, b, acc[0][t], 0, 0, 0);
                    acc[1][t] = __builtin_amdgcn_mfma_f32_16x16x32_bf16(a1, b, acc[1][t], 0, 0, 0);
                }
            }
        }
        #pragma unroll
        for (int t = 0; t < 13; ++t) {
            int tile = nt0 + t;
            if (tile < 50) {
                int col = tile * 16 + lr;
                float badd = (col >= WOUT) ? edge_b[col - WOUT] : 0.f;
                #pragma unroll
                for (int m = 0; m < 2; ++m) {
                    #pragma unroll
                    for (int r = 0; r < 4; ++r) {
                        int n = n0 + m * 16 + rbase + r;
                        if (n < NN) srcdst[(size_t)n * 800 + col] = f2bf(acc[m][t][r] + badd);
                    }
                }
            }
        }
    }

    // ---- ada: 37 tiles, K=128
    {
        const int nt0a = wid * 9;
        f32x4 acc2[2][10];
        #pragma unroll
        for (int m = 0; m < 2; ++m)
            #pragma unroll
            for (int t = 0; t < 10; ++t) acc2[m][t] = (f32x4){0.f, 0.f, 0.f, 0.f};

        for (int ks = 0; ks < 4; ++ks) {
            int kin = ks * 32 + lkb;
            bf16x8 a0 = *(const bf16x8*)&As2[lr * AP2 + 256 + kin];
            bf16x8 a1 = *(const bf16x8*)&As2[(16 + lr) * AP2 + 256 + kin];
            #pragma unroll
            for (int t = 0; t < 10; ++t) {
                int tile = nt0a + t;
                if (tile < 37) {
                    bf16x8 b = *(const bf16x8*)&Ba[(size_t)(tile * 16 + lr) * 128 + kin];
                    acc2[0][t] = __builtin_amdgcn_mfma_f32_16x16x32_bf16(a0, b, acc2[0][t], 0, 0, 0);
                    acc2[1][t] = __builtin_amdgcn_mfma_f32_16x16x32_bf16(a1, b, acc2[1][t], 0, 0, 0);
                }
            }
        }
        #pragma unroll
        for (int t = 0; t < 10; ++t) {
            int tile = nt0a + t;
            if (tile < 37) {
                int col = tile * 16 + lr;
                float badd = adab[col];
                #pragma unroll
                for (int m = 0; m < 2; ++m) {
                    #pragma unroll
                    for (int r = 0; r < 4; ++r) {
                        int n = n0 + m * 16 + rbase + r;
                        if (n < NN) ada_out[(size_t)n * ADA + col] = acc2[m][t][r] + badd;
                    }
                }
            }
        }
    }

    // ---- sv: 2 tiles (waves 0,1), K=256
    if (wid < 2) {
        f32x4 accs[2];
        accs[0] = (f32x4){0.f, 0.f, 0.f, 0.f};
        accs[1] = (f32x4){0.f, 0.f, 0.f, 0.f};
        for (int ks = 0; ks < 8; ++ks) {
            int kb = ks * 32 + lkb;
            bf16x8 a0 = *(const bf16x8*)&As2[lr * AP2 + kb];
            bf16x8 a1 = *(const bf16x8*)&As2[(16 + lr) * AP2 + kb];
            bf16x8 b = *(const bf16x8*)&Bsv[(size_t)(wid * 16 + lr) * 256 + kb];
            accs[0] = __builtin_amdgcn_mfma_f32_16x16x32_bf16(a0, b, accs[0], 0, 0, 0);
            accs[1] = __builtin_amdgcn_mfma_f32_16x16x32_bf16(a1, b, accs[1], 0, 0, 0);
        }
        int col = wid * 16 + lr;
        #pragma unroll
        for (int m = 0; m < 2; ++m) {
            #pragma unroll
            for (int r = 0; r < 4; ++r) {
                int n = n0 + m * 16 + rbase + r;
                if (n < NN) sv[(size_t)n * VDIM + col] = accs[m][r];
            }
        }
    }
}

// ================================================================ edge kernel
__global__ __launch_bounds__(256) void edge_kernel(
    const unsigned short* __restrict__ hb, const float* __restrict__ coords,
    const float* __restrict__ erd, const float* __restrict__ sv,
    const unsigned short* __restrict__ Wt1, const unsigned short* __restrict__ srcdst,
    const int* __restrict__ perm, const int* __restrict__ eidx,
    const int* __restrict__ etype, const int* __restrict__ ebt,
    const int* __restrict__ ebc, const int* __restrict__ ebr,
    const int* __restrict__ ebs,
    const float* __restrict__ etype_emb, const float* __restrict__ btype_emb,
    const float* __restrict__ bconj_emb, const float* __restrict__ bring_emb,
    const float* __restrict__ bstereo_emb,
    const float* __restrict__ refW, const float* __restrict__ refb,
    float* __restrict__ agg)
{
    __shared__ unsigned short wl[ETM * WLP];     // 12.9 KB (bf16 w)
    __shared__ unsigned short As[ETM * AP1];     // 2.3 KB
    __shared__ int srcl[ETM], dstl[ETM];
    __shared__ int itype[ETM], ibt[ETM], ibc[ETM], ibr[ETM], ibs[ETM];
    __shared__ float distl[ETM], erdl[ETM], y1l[ETM][3];

    const int tid = threadIdx.x;
    const int e0 = blockIdx.x * ETM;

    if (tid < ETM) {
        int ge = perm[e0 + tid];
        int s = eidx[ge], d = eidx[NE + ge];
        srcl[tid] = s; dstl[tid] = d;
        itype[tid] = etype[ge]; ibt[tid] = ebt[ge]; ibc[tid] = ebc[ge];
        ibr[tid] = ebr[ge]; ibs[tid] = ebs[ge];
        float dx = coords[d*3+0] - coords[s*3+0];
        float dy = coords[d*3+1] - coords[s*3+1];
        float dz = coords[d*3+2] - coords[s*3+2];
        float dist = sqrtf(dx*dx + dy*dy + dz*dz);
        distl[tid] = dist;
        float inv = 1.f / (dist + 1e-8f);
        y1l[tid][0] = dx * inv; y1l[tid][1] = dy * inv; y1l[tid][2] = dz * inv;
        erdl[tid] = erd[ge];
    }
    __syncthreads();

    // ---- stage misc features (k<60, padded to 64) as bf16
    {
        const int k = tid & 63;
        const int ebase = tid >> 6;
        #pragma unroll
        for (int it = 0; it < 4; ++it) {
            int e = it * 4 + ebase;
            float de = distl[e];
            float v;
            if (k >= 60) v = 0.f;
            else if (k < 16) { float x = (de - (float)k * (10.f/15.f)) * 1.6f; v = expf(-x*x); }
            else if (k < 32) v = etype_emb[itype[e]*16 + (k-16)];
            else if (k < 40) v = btype_emb[ibt[e]*8 + (k-32)];
            else if (k < 44) v = bconj_emb[ibc[e]*4 + (k-40)];
            else if (k < 48) v = bring_emb[ibr[e]*4 + (k-44)];
            else if (k < 52) v = bstereo_emb[ibs[e]*4 + (k-48)];
            else {
                int j = k - 52;
                float dd = de - erdl[e];
                float hr = erdl[e] > 0.f ? 1.f : 0.f;
                v = fabsf(dd)*refW[j] + dd*refW[8+j] + hr*refW[16+j] + refb[j];
            }
            As[e * AP1 + k] = f2bf(v);
        }
    }
    __syncthreads();

    // ---- tiny MFMA GEMM (misc) + fused srcdst gather-add, all in epilogue
    const int wid = tid >> 6, lane = tid & 63;
    const int lr = lane & 15, lkb = (lane >> 4) << 3;
    const int nt0 = wid * 6;                  // 25 tiles / 4 waves, 7 each (overlap dup)
    {
        f32x4 acc[7];
        #pragma unroll
        for (int t = 0; t < 7; ++t) acc[t] = (f32x4){0.f, 0.f, 0.f, 0.f};

        #pragma unroll
        for (int ks = 0; ks < 2; ++ks) {
            int kb = ks * 32 + lkb;
            bf16x8 a0 = *(const bf16x8*)&As[lr * AP1 + kb];
            #pragma unroll
            for (int t = 0; t < 7; ++t) {
                bf16x8 b = *(const bf16x8*)&Wt1[(size_t)((nt0 + t) * 16 + lr) * 64 + kb];
                acc[t] = __builtin_amdgcn_mfma_f32_16x16x32_bf16(a0, b, acc[t], 0, 0, 0);
            }
        }
        const int rbase = (lane >> 4) << 2;
        int se[4], de_[4];
        #pragma unroll
        for (int r = 0; r < 4; ++r) { se[r] = srcl[rbase + r]; de_[r] = dstl[rbase + r]; }
        #pragma unroll
        for (int t = 0; t < 7; ++t) {
            const int col = (nt0 + t) * 16 + lr;
            #pragma unroll
            for (int r = 0; r < 4; ++r) {
                float add = bf2f(srcdst[(size_t)se[r] * 800 + col])
                          + bf2f(srcdst[(size_t)de_[r] * 800 + 400 + col]);
                wl[(rbase + r) * WLP + col] = f2bf(acc[t][r] + add);
            }
        }
    }
    __syncthreads();

    // ---- messages with run-accumulation (edges sorted by dst)
    {
        int cls = 0, cc = 0, ii = 0, ia = 0, ib = 0, hoff = 0, wB1 = 0, wB2 = 0;
        if (tid < 96)       { cls = 0; cc = tid / 3;        ii = tid % 3;        hoff = 256 + tid; wB1 = 256 + cc; wB2 = 288 + cc; }
        else if (tid < 192) { int j = tid - 96; cls = 1; cc = j / 3; ii = j % 3; hoff = 352 + j;   wB1 = 320 + cc; wB2 = 352 + cc; }
        else                { int j = tid - 192; cls = 2; cc = j / 5;            hoff = 448 + j;   wB1 = 384 + cc; }
        ia = (ii + 1) % 3; ib = (ii + 2) % 3;

        const bool hasC = tid < 16;
        const int jC = 64 + tid;          // l2 channel slot 64..79
        const int hoffC = 448 + jC;       // feature offset 512..527
        const int wC = 384 + jC / 5;

        float accA = 0.f, accB = 0.f, accC = 0.f;
        for (int e = 0; e < ETM; ++e) {
            const int src = srcl[e];
            const unsigned short* hs = hb + (size_t)src * FEAT;
            accA = fmaf(bf2f(wl[e * WLP + tid]), bf2f(hs[tid]), accA);
            float m;
            if (cls == 0) {
                float wv1 = bf2f(wl[e * WLP + wB1]), wsv = bf2f(wl[e * WLP + wB2]);
                m = wv1 * bf2f(hs[hoff]) + wsv * sv[(size_t)src * VDIM + cc] * y1l[e][ii];
            } else if (cls == 1) {
                float wv2 = bf2f(wl[e * WLP + wB1]), wcx = bf2f(wl[e * WLP + wB2]);
                float va = bf2f(hs[256 + cc * 3 + ia]), vb = bf2f(hs[256 + cc * 3 + ib]);
                m = wv2 * bf2f(hs[hoff]) + wcx * (va * y1l[e][ib] - vb * y1l[e][ia]);
            } else {
                m = bf2f(wl[e * WLP + wB1]) * bf2f(hs[hoff]);
            }
            accB += m;
            if (hasC) accC = fmaf(bf2f(wl[e * WLP + wC]), bf2f(hs[hoffC]), accC);

            bool fl = (e == ETM - 1) || (dstl[e + 1] != dstl[e]);
            if (fl) {
                int d = dstl[e];
                atomicAdd(&agg[(size_t)d * FEAT + tid], accA);
                atomicAdd(&agg[(size_t)d * FEAT + 256 + tid], accB);
                if (hasC) atomicAdd(&agg[(size_t)d * FEAT + hoffC], accC);
                accA = 0.f; accB = 0.f; accC = 0.f;
            }
        }
    }
}

// ================================================================ proj kernel: us = silu(agg_s*DEG_INV @ proj_s)
__global__ __launch_bounds__(256) void proj_kernel(
    const float* __restrict__ agg, const unsigned short* __restrict__ Ps,
    float* __restrict__ us_buf)
{
    __shared__ unsigned short As3[32 * AP3];
    const int tid = threadIdx.x;
    const int n0 = blockIdx.x * 32;

    for (int e = 0; e < 32; ++e) {
        int n = n0 + e;
        float v = (n < NN) ? agg[(size_t)n * FEAT + tid] * DEG_INV : 0.f;
        As3[e * AP3 + tid] = f2bf(v);
    }
    __syncthreads();

    const int wid = tid >> 6, lane = tid & 63;
    const int lr = lane & 15, lkb = (lane >> 4) << 3;
    const int rbase = (lane >> 4) << 2;
    const int nt0 = wid * 4;          // 16 tiles over 4 waves

    f32x4 acc[2][4];
    #pragma unroll
    for (int m = 0; m < 2; ++m)
        #pragma unroll
        for (int t = 0; t < 4; ++t) acc[m][t] = (f32x4){0.f, 0.f, 0.f, 0.f};

    for (int ks = 0; ks < 8; ++ks) {
        int kb = ks * 32 + lkb;
        bf16x8 a0 = *(const bf16x8*)&As3[lr * AP3 + kb];
        bf16x8 a1 = *(const bf16x8*)&As3[(16 + lr) * AP3 + kb];
        #pragma unroll
        for (int t = 0; t < 4; ++t) {
            bf16x8 b = *(const bf16x8*)&Ps[(size_t)((nt0 + t) * 16 + lr) * 256 + kb];
            acc[0][t] = __builtin_amdgcn_mfma_f32_16x16x32_bf16(a0, b, acc[0][t], 0, 0, 0);
            acc[1][t] = __builtin_amdgcn_mfma_f32_16x16x32_bf16(a1, b, acc[1][t], 0, 0, 0);
        }
    }
    #pragma unroll
    for (int t = 0; t < 4; ++t) {
        int col = (nt0 + t) * 16 + lr;
        #pragma unroll
        for (int m = 0; m < 2; ++m) {
            #pragma unroll
            for (int r = 0; r < 4; ++r) {
                int n = n0 + m * 16 + rbase + r;
                if (n < NN) {
                    float x = acc[m][t][r];
                    us_buf[(size_t)n * SDIM + col] = x / (1.f + expf(-x));
                }
            }
        }
    }
}

// ================================================================ node kernel
__device__ __forceinline__ float block_reduce_sum(float v, float* red, int tid) {
    #pragma unroll
    for (int off = 32; off > 0; off >>= 1) v += __shfl_down(v, off, 64);
    if ((tid & 63) == 0) red[tid >> 6] = v;
    __syncthreads();
    float s = red[0] + red[1] + red[2] + red[3];
    __syncthreads();
    return s;
}

__global__ __launch_bounds__(256) void node_kernel(
    const float* __restrict__ hcur, const float* __restrict__ ada_buf,
    const float* __restrict__ agg, const float* __restrict__ us_buf,
    const float* __restrict__ proj_v1, const float* __restrict__ proj_v2,
    const float* __restrict__ proj_l2,
    float* __restrict__ hnext, unsigned short* __restrict__ hbnext)
{
    const int n = blockIdx.x;
    const int tid = threadIdx.x;
    __shared__ float ada[ADA];
    __shared__ float av[272];
    __shared__ float vbuf[272];
    __shared__ float red[8];

    for (int i = tid; i < 272; i += 256)
        av[i] = agg[(size_t)n * FEAT + 256 + i] * DEG_INV;
    for (int r = 0; r < 3; ++r) {
        int col = r * 256 + tid;
        if (col < ADA) ada[col] = ada_buf[(size_t)n * ADA + col];
    }
    __syncthreads();

    float sn = hcur[(size_t)n * FEAT + tid] + us_buf[(size_t)n * SDIM + tid];

    if (tid < 96) {
        int d = tid / 3, i = tid - d * 3;
        float a = 0.f;
        #pragma unroll
        for (int c = 0; c < VDIM; ++c) a = fmaf(av[c*3 + i], proj_v1[c * VDIM + d], a);
        vbuf[tid] = hcur[(size_t)n * FEAT + SDIM + tid] + a;
    } else if (tid < 192) {
        int t2 = tid - 96;
        int d = t2 / 3, i = t2 - d * 3;
        float a = 0.f;
        #pragma unroll
        for (int c = 0; c < VDIM; ++c) a = fmaf(av[96 + c*3 + i], proj_v2[c * VDIM + d], a);
        vbuf[tid] = hcur[(size_t)n * FEAT + SDIM + 3*VDIM + t2] + a;
    }
    if (tid < 80) {
        int d = tid / 5, i = tid - d * 5;
        float a = 0.f;
        #pragma unroll
        for (int c = 0; c < L2DIM; ++c) a = fmaf(av[192 + c*5 + i], proj_l2[c * L2DIM + d], a);
        vbuf[192 + tid] = hcur[(size_t)n * FEAT + SDIM + 6*VDIM + tid] + a;
    }
    __syncthreads();

    float ssum = block_reduce_sum(sn, red, tid);
    float ssq  = block_reduce_sum(sn * sn, red, tid);
    float mu = ssum * (1.f / SDIM);
    float var = ssq * (1.f / SDIM) - mu * mu;
    float rstd = rsqrtf(var + 1e-5f);
    {
        float o = (sn - mu) * rstd * (1.f + ada[tid]) + ada[SDIM + tid];
        hnext[(size_t)n * FEAT + tid] = o;
        if (hbnext) hbnext[(size_t)n * FEAT + tid] = f2bf(o);
    }

    float q1 = (tid < 96) ? vbuf[tid] * vbuf[tid] : 0.f;
    float S1 = block_reduce_sum(q1, red, tid);
    float q2 = (tid >= 96 && tid < 192) ? vbuf[tid] * vbuf[tid] : 0.f;
    float S2 = block_reduce_sum(q2, red, tid);
    float q3 = (tid < 80) ? vbuf[192 + tid] * vbuf[192 + tid] : 0.f;
    float S3 = block_reduce_sum(q3, red, tid);

    float r1 = rsqrtf(S1 * (1.f / VDIM) + 1e-5f);
    float r2 = rsqrtf(S2 * (1.f / VDIM) + 1e-5f);
    float r3 = rsqrtf(S3 * (1.f / L2DIM) + 1e-5f);

    if (tid < 96) {
        int d = tid / 3;
        float o = vbuf[tid] * r1 * (1.f + ada[2*SDIM + d]);
        hnext[(size_t)n * FEAT + SDIM + tid] = o;
        if (hbnext) hbnext[(size_t)n * FEAT + SDIM + tid] = f2bf(o);
    } else if (tid < 192) {
        int t2 = tid - 96;
        int d = t2 / 3;
        float o = vbuf[tid] * r2 * (1.f + ada[2*SDIM + VDIM + d]);
        hnext[(size_t)n * FEAT + SDIM + 3*VDIM + t2] = o;
        if (hbnext) hbnext[(size_t)n * FEAT + SDIM + 3*VDIM + t2] = f2bf(o);
    }
    if (tid < 80) {
        int d = tid / 5;
        float o = vbuf[192 + tid] * r3 * (1.f + ada[2*SDIM + 2*VDIM + d]);
        hnext[(size_t)n * FEAT + SDIM + 6*VDIM + tid] = o;
        if (hbnext) hbnext[(size_t)n * FEAT + SDIM + 6*VDIM + tid] = f2bf(o);
    }
}

// ================================================================ launch
extern "C" void kernel_launch(void* const* d_in, const int* in_sizes, int n_in,
                              void* d_out, int out_size, void* d_ws, size_t ws_size,
                              hipStream_t stream) {
    const float* h_in   = (const float*)d_in[0];
    const float* coords = (const float*)d_in[1];
    const float* erd    = (const float*)d_in[2];
    const float* t_emb  = (const float*)d_in[3];
    const float* etype_emb   = (const float*)d_in[4];
    const float* btype_emb   = (const float*)d_in[5];
    const float* bconj_emb   = (const float*)d_in[6];
    const float* bring_emb   = (const float*)d_in[7];
    const float* bstereo_emb = (const float*)d_in[8];
    const float* refW   = (const float*)d_in[9];
    const float* refb   = (const float*)d_in[10];
    const float* edgeW  = (const float*)d_in[11];
    const float* edgeb  = (const float*)d_in[12];
    const float* svW    = (const float*)d_in[13];
    const float* proj_s = (const float*)d_in[14];
    const float* proj_v1= (const float*)d_in[15];
    const float* proj_v2= (const float*)d_in[16];
    const float* proj_l2= (const float*)d_in[17];
    const float* adaW   = (const float*)d_in[18];
    const float* adab   = (const float*)d_in[19];
    const int* eidx     = (const int*)d_in[20];
    const int* etype    = (const int*)d_in[21];
    const int* ebt      = (const int*)d_in[22];
    const int* ebc      = (const int*)d_in[23];
    const int* ebr      = (const int*)d_in[24];
    const int* ebs      = (const int*)d_in[25];

    float* ws_f     = (float*)d_ws;
    float* sv       = ws_f;                           // N*32
    float* agg      = sv + (size_t)NN * VDIM;         // N*528
    float* h1       = agg + (size_t)NN * FEAT;        // N*528
    float* ada_buf  = h1 + (size_t)NN * FEAT;         // N*592
    float* us_buf   = ada_buf + (size_t)NN * ADA;     // N*256
    unsigned short* srcdst = (unsigned short*)(us_buf + (size_t)NN * SDIM);  // N*800
    unsigned short* hb     = srcdst + (size_t)NN * 800;                      // N*528
    unsigned short* Wt1    = hb + (size_t)NN * FEAT;                         // 400*64
    unsigned short* Bn     = Wt1 + (size_t)WOUT * 64;                        // 800*384
    unsigned short* Ba     = Bn + (size_t)800 * 384;                         // 592*128
    unsigned short* Bsv    = Ba + (size_t)ADA * 128;                         // 32*256
    unsigned short* Ps     = Bsv + (size_t)VDIM * 256;                       // 256*256
    int* cnt    = (int*)(Ps + (size_t)SDIM * 256);    // N
    int* cursor = cnt + NN;                           // N
    int* perm   = cursor + NN;                        // E

    // ---- sort edges by dst (once; reused by both layers)
    hipMemsetAsync(cnt, 0, NN * sizeof(int), stream);
    hist_kernel<<<(NE + 255) / 256, 256, 0, stream>>>(eidx, cnt);
    scan_kernel<<<1, 1024, 0, stream>>>(cnt, cursor);
    scatter_kernel<<<(NE + 255) / 256, 256, 0, stream>>>(eidx, cursor, perm);
    hb_kernel<<<(NN * FEAT / 4 + 255) / 256, 256, 0, stream>>>(h_in, hb);

    for (int l = 0; l < 2; ++l) {
        const float* hcur = (l == 0) ? h_in : h1;
        float* hnext      = (l == 0) ? h1 : (float*)d_out;
        const float* W    = edgeW + (size_t)l * 700 * WOUT;

        hipMemsetAsync(agg, 0, (size_t)NN * FEAT * sizeof(float), stream);
        prep_kernel<<<(O5 + 255) / 256, 256, 0, stream>>>(
            W, adaW + (size_t)l * TDIM * ADA, svW + (size_t)l * SDIM * VDIM,
            proj_s + (size_t)l * SDIM * SDIM, Wt1, Bn, Ba, Bsv, Ps);
        nodeproj_kernel<<<(NN + 31) / 32, 256, 0, stream>>>(
            hb, t_emb, Bn, Ba, Bsv, edgeb + l * WOUT, adab + l * ADA,
            srcdst, ada_buf, sv);
        edge_kernel<<<NE / ETM, 256, 0, stream>>>(
            hb, coords, erd, sv, Wt1, srcdst, perm,
            eidx, etype, ebt, ebc, ebr, ebs,
            etype_emb + l * 144, btype_emb + l * 48, bconj_emb + l * 12,
            bring_emb + l * 12, bstereo_emb + l * 20,
            refW + l * 24, refb + l * 8,
            agg);
        proj_kernel<<<(NN + 31) / 32, 256, 0, stream>>>(agg, Ps, us_buf);
        node_kernel<<<NN, 256, 0, stream>>>(
            hcur, ada_buf, agg, us_buf,
            proj_v1 + l * VDIM * VDIM, proj_v2 + l * VDIM * VDIM,
            proj_l2 + l * L2DIM * L2DIM,
            hnext, (l == 0) ? hb : (unsigned short*)nullptr);
    }
}

// Round 7
// 762.517 us; speedup vs baseline: 5.8311x; 1.1405x over previous
//
#include <hip/hip_runtime.h>
#include <math.h>

#define NN 10000
#define NE 160000
#define SDIM 256
#define VDIM 32
#define L2DIM 16
#define TDIM 128
#define FEAT 528      // S + 3V + 3V + 5*L2
#define WOUT 400      // S + 4V + L2
#define ADA 592       // 2S+2V+L2
#define DEG_INV 0.25f

#define ETM 16        // edges per block
#define WLP 404       // w LDS stride (bf16 elems)
#define AP1 72        // misc A stride (bf16)
#define AP2 392       // nodeproj A stride (bf16)
#define AP3 264       // proj kernel A stride (bf16)
#define HSP 536       // staged h row stride (bf16 elems, 528+8)

typedef short bf16x8 __attribute__((ext_vector_type(8)));
typedef float f32x4 __attribute__((ext_vector_type(4)));

__device__ __forceinline__ unsigned short f2bf(float f) {
    unsigned int u = __float_as_uint(f);
    u += 0x7fffu + ((u >> 16) & 1u);      // round-to-nearest-even
    return (unsigned short)(u >> 16);
}
__device__ __forceinline__ float bf2f(unsigned short b) {
    return __uint_as_float(((unsigned int)b) << 16);
}

// ================================================================ sort by dst
__global__ __launch_bounds__(256) void hist_kernel(const int* __restrict__ eidx,
                                                   int* __restrict__ cnt) {
    int e = blockIdx.x * 256 + threadIdx.x;
    if (e < NE) atomicAdd(&cnt[eidx[NE + e]], 1);
}

__global__ __launch_bounds__(1024) void scan_kernel(const int* __restrict__ cnt,
                                                    int* __restrict__ cursor) {
    __shared__ int sc[1024];
    int tid = threadIdx.x;
    int base = tid * 10;
    int loc[10];
    int s = 0;
    if (base < NN) {
        #pragma unroll
        for (int j = 0; j < 10; ++j) { loc[j] = cnt[base + j]; s += loc[j]; }
    }
    sc[tid] = s;
    __syncthreads();
    for (int off = 1; off < 1024; off <<= 1) {
        int v = sc[tid];
        int add = (tid >= off) ? sc[tid - off] : 0;
        __syncthreads();
        sc[tid] = v + add;
        __syncthreads();
    }
    int run = sc[tid] - s;   // exclusive prefix
    if (base < NN) {
        #pragma unroll
        for (int j = 0; j < 10; ++j) { cursor[base + j] = run; run += loc[j]; }
    }
}

__global__ __launch_bounds__(256) void scatter_kernel(const int* __restrict__ eidx,
                                                      int* __restrict__ cursor,
                                                      int* __restrict__ perm) {
    int e = blockIdx.x * 256 + threadIdx.x;
    if (e < NE) {
        int d = eidx[NE + e];
        int p = atomicAdd(&cursor[d], 1);
        perm[p] = e;
    }
}

// ================================================================ fused weight prep
// Wt1[400][64], Bn[800][384], Ba[592][128], Bsv[32][256], Ps[256][256]
#define O1 25600
#define O2 332800
#define O3 408576
#define O4 416768
#define O5 482304
__global__ __launch_bounds__(256) void prep_kernel(
    const float* __restrict__ W, const float* __restrict__ adaW,
    const float* __restrict__ svW, const float* __restrict__ projs,
    unsigned short* __restrict__ Wt1, unsigned short* __restrict__ Bn,
    unsigned short* __restrict__ Ba, unsigned short* __restrict__ Bsv,
    unsigned short* __restrict__ Ps)
{
    int idx = blockIdx.x * 256 + threadIdx.x;
    if (idx < O1) {
        int c = idx >> 6, k = idx & 63;
        float v = (k < 60) ? W[(size_t)k * WOUT + c] : 0.f;
        Wt1[idx] = f2bf(v);
    } else if (idx < O2) {
        int i = idx - O1;
        int c = i / 384, k = i - c * 384;
        float v;
        if (c < WOUT) v = (k < 256) ? W[(size_t)(60 + k) * WOUT + c] : 0.f;
        else {
            int c2 = c - WOUT;
            v = (k < 256) ? W[(size_t)(316 + k) * WOUT + c2]
                          : W[(size_t)(572 + (k - 256)) * WOUT + c2];
        }
        Bn[i] = f2bf(v);
    } else if (idx < O3) {
        int i = idx - O2;
        int c = i >> 7, k = i & 127;
        Ba[i] = f2bf(adaW[(size_t)k * ADA + c]);
    } else if (idx < O4) {
        int i = idx - O3;
        int c = i >> 8, k = i & 255;
        Bsv[i] = f2bf(svW[(size_t)k * VDIM + c]);
    } else if (idx < O5) {
        int i = idx - O4;
        int c = i >> 8, k = i & 255;
        Ps[i] = f2bf(projs[(size_t)k * SDIM + c]);
    }
}

// ================================================================ hb = bf16(h) (input layer only)
struct us4 { unsigned short x, y, z, w; };
__global__ __launch_bounds__(256) void hb_kernel(const float* __restrict__ h,
                                                 unsigned short* __restrict__ hb) {
    int i = blockIdx.x * 256 + threadIdx.x;
    if (i >= NN * FEAT / 4) return;
    float4 v = ((const float4*)h)[i];
    us4 o;
    o.x = f2bf(v.x); o.y = f2bf(v.y); o.z = f2bf(v.z); o.w = f2bf(v.w);
    ((us4*)hb)[i] = o;
}

// ================================================================ nodeproj: srcdst (bf16) + ada (f32) + sv (f32)
__global__ __launch_bounds__(256) void nodeproj_kernel(
    const unsigned short* __restrict__ hb, const float* __restrict__ t_emb,
    const unsigned short* __restrict__ Bn, const unsigned short* __restrict__ Ba,
    const unsigned short* __restrict__ Bsv,
    const float* __restrict__ edge_b, const float* __restrict__ adab,
    unsigned short* __restrict__ srcdst, float* __restrict__ ada_out,
    float* __restrict__ sv)
{
    __shared__ unsigned short As2[32 * AP2];
    const int tid = threadIdx.x;
    const int n0 = blockIdx.x * 32;

    for (int e = 0; e < 32; ++e) {
        int n = n0 + e;
        As2[e * AP2 + tid] = (n < NN) ? hb[(size_t)n * FEAT + tid] : 0;
        if (tid < 128) {
            float v1 = (n < NN) ? t_emb[(size_t)n * TDIM + tid] : 0.f;
            As2[e * AP2 + 256 + tid] = f2bf(v1);
        }
    }
    __syncthreads();

    const int wid = tid >> 6, lane = tid & 63;
    const int lr = lane & 15, lkb = (lane >> 4) << 3;
    const int rbase = (lane >> 4) << 2;

    // ---- main: 50 tiles, K=384
    {
        const int nt0 = wid * 13;
        f32x4 acc[2][13];
        #pragma unroll
        for (int m = 0; m < 2; ++m)
            #pragma unroll
            for (int t = 0; t < 13; ++t) acc[m][t] = (f32x4){0.f, 0.f, 0.f, 0.f};

        for (int ks = 0; ks < 12; ++ks) {
            int kb = ks * 32 + lkb;
            bf16x8 a0 = *(const bf16x8*)&As2[lr * AP2 + kb];
            bf16x8 a1 = *(const bf16x8*)&As2[(16 + lr) * AP2 + kb];
            #pragma unroll
            for (int t = 0; t < 13; ++t) {
                int tile = nt0 + t;
                if (tile < 50) {
                    bf16x8 b = *(const bf16x8*)&Bn[(size_t)(tile * 16 + lr) * 384 + kb];
                    acc[0][t] = __builtin_amdgcn_mfma_f32_16x16x32_bf16(a0, b, acc[0][t], 0, 0, 0);
                    acc[1][t] = __builtin_amdgcn_mfma_f32_16x16x32_bf16(a1, b, acc[1][t], 0, 0, 0);
                }
            }
        }
        #pragma unroll
        for (int t = 0; t < 13; ++t) {
            int tile = nt0 + t;
            if (tile < 50) {
                int col = tile * 16 + lr;
                float badd = (col >= WOUT) ? edge_b[col - WOUT] : 0.f;
                #pragma unroll
                for (int m = 0; m < 2; ++m) {
                    #pragma unroll
                    for (int r = 0; r < 4; ++r) {
                        int n = n0 + m * 16 + rbase + r;
                        if (n < NN) srcdst[(size_t)n * 800 + col] = f2bf(acc[m][t][r] + badd);
                    }
                }
            }
        }
    }

    // ---- ada: 37 tiles, K=128
    {
        const int nt0a = wid * 9;
        f32x4 acc2[2][10];
        #pragma unroll
        for (int m = 0; m < 2; ++m)
            #pragma unroll
            for (int t = 0; t < 10; ++t) acc2[m][t] = (f32x4){0.f, 0.f, 0.f, 0.f};

        for (int ks = 0; ks < 4; ++ks) {
            int kin = ks * 32 + lkb;
            bf16x8 a0 = *(const bf16x8*)&As2[lr * AP2 + 256 + kin];
            bf16x8 a1 = *(const bf16x8*)&As2[(16 + lr) * AP2 + 256 + kin];
            #pragma unroll
            for (int t = 0; t < 10; ++t) {
                int tile = nt0a + t;
                if (tile < 37) {
                    bf16x8 b = *(const bf16x8*)&Ba[(size_t)(tile * 16 + lr) * 128 + kin];
                    acc2[0][t] = __builtin_amdgcn_mfma_f32_16x16x32_bf16(a0, b, acc2[0][t], 0, 0, 0);
                    acc2[1][t] = __builtin_amdgcn_mfma_f32_16x16x32_bf16(a1, b, acc2[1][t], 0, 0, 0);
                }
            }
        }
        #pragma unroll
        for (int t = 0; t < 10; ++t) {
            int tile = nt0a + t;
            if (tile < 37) {
                int col = tile * 16 + lr;
                float badd = adab[col];
                #pragma unroll
                for (int m = 0; m < 2; ++m) {
                    #pragma unroll
                    for (int r = 0; r < 4; ++r) {
                        int n = n0 + m * 16 + rbase + r;
                        if (n < NN) ada_out[(size_t)n * ADA + col] = acc2[m][t][r] + badd;
                    }
                }
            }
        }
    }

    // ---- sv: 2 tiles (waves 0,1), K=256
    if (wid < 2) {
        f32x4 accs[2];
        accs[0] = (f32x4){0.f, 0.f, 0.f, 0.f};
        accs[1] = (f32x4){0.f, 0.f, 0.f, 0.f};
        for (int ks = 0; ks < 8; ++ks) {
            int kb = ks * 32 + lkb;
            bf16x8 a0 = *(const bf16x8*)&As2[lr * AP2 + kb];
            bf16x8 a1 = *(const bf16x8*)&As2[(16 + lr) * AP2 + kb];
            bf16x8 b = *(const bf16x8*)&Bsv[(size_t)(wid * 16 + lr) * 256 + kb];
            accs[0] = __builtin_amdgcn_mfma_f32_16x16x32_bf16(a0, b, accs[0], 0, 0, 0);
            accs[1] = __builtin_amdgcn_mfma_f32_16x16x32_bf16(a1, b, accs[1], 0, 0, 0);
        }
        int col = wid * 16 + lr;
        #pragma unroll
        for (int m = 0; m < 2; ++m) {
            #pragma unroll
            for (int r = 0; r < 4; ++r) {
                int n = n0 + m * 16 + rbase + r;
                if (n < NN) sv[(size_t)n * VDIM + col] = accs[m][r];
            }
        }
    }
}

// ================================================================ edge kernel
__global__ __launch_bounds__(256) void edge_kernel(
    const unsigned short* __restrict__ hb, const float* __restrict__ coords,
    const float* __restrict__ erd, const float* __restrict__ sv,
    const unsigned short* __restrict__ Wt1, const unsigned short* __restrict__ srcdst,
    const int* __restrict__ perm, const int* __restrict__ eidx,
    const int* __restrict__ etype, const int* __restrict__ ebt,
    const int* __restrict__ ebc, const int* __restrict__ ebr,
    const int* __restrict__ ebs,
    const float* __restrict__ etype_emb, const float* __restrict__ btype_emb,
    const float* __restrict__ bconj_emb, const float* __restrict__ bring_emb,
    const float* __restrict__ bstereo_emb,
    const float* __restrict__ refW, const float* __restrict__ refb,
    float* __restrict__ agg)
{
    __shared__ unsigned short wl[ETM * WLP];     // 12.9 KB (bf16 w)
    __shared__ unsigned short hsl[ETM * HSP];    // 17.2 KB staged src rows
    __shared__ float svl[ETM * VDIM];            // 2 KB staged sv rows
    __shared__ unsigned short As[ETM * AP1];     // 2.3 KB
    __shared__ int srcl[ETM], dstl[ETM];
    __shared__ int itype[ETM], ibt[ETM], ibc[ETM], ibr[ETM], ibs[ETM];
    __shared__ float distl[ETM], erdl[ETM], y1l[ETM][3];

    const int tid = threadIdx.x;
    const int e0 = blockIdx.x * ETM;

    if (tid < ETM) {
        int ge = perm[e0 + tid];
        int s = eidx[ge], d = eidx[NE + ge];
        srcl[tid] = s; dstl[tid] = d;
        itype[tid] = etype[ge]; ibt[tid] = ebt[ge]; ibc[tid] = ebc[ge];
        ibr[tid] = ebr[ge]; ibs[tid] = ebs[ge];
        float dx = coords[d*3+0] - coords[s*3+0];
        float dy = coords[d*3+1] - coords[s*3+1];
        float dz = coords[d*3+2] - coords[s*3+2];
        float dist = sqrtf(dx*dx + dy*dy + dz*dz);
        distl[tid] = dist;
        float inv = 1.f / (dist + 1e-8f);
        y1l[tid][0] = dx * inv; y1l[tid][1] = dy * inv; y1l[tid][2] = dz * inv;
        erdl[tid] = erd[ge];
    }
    __syncthreads();

    // ---- bulk-stage src rows of hb into LDS (all loads in flight at once)
    {
        // 16 rows x 66 x bf16x8 (16B) = 1056 vec loads over 256 threads
        for (int i = tid; i < ETM * 66; i += 256) {
            int e = i / 66, j = i - e * 66;
            bf16x8 v = *(const bf16x8*)&hb[(size_t)srcl[e] * FEAT + j * 8];
            *(bf16x8*)&hsl[e * HSP + j * 8] = v;
        }
        // sv rows: 16 x 32 f32
        for (int i = tid; i < ETM * VDIM; i += 256) {
            int e = i >> 5, c = i & 31;
            svl[i] = sv[(size_t)srcl[e] * VDIM + c];
        }
    }

    // ---- stage misc features (k<60, padded to 64) as bf16
    {
        const int k = tid & 63;
        const int ebase = tid >> 6;
        #pragma unroll
        for (int it = 0; it < 4; ++it) {
            int e = it * 4 + ebase;
            float de = distl[e];
            float v;
            if (k >= 60) v = 0.f;
            else if (k < 16) { float x = (de - (float)k * (10.f/15.f)) * 1.6f; v = expf(-x*x); }
            else if (k < 32) v = etype_emb[itype[e]*16 + (k-16)];
            else if (k < 40) v = btype_emb[ibt[e]*8 + (k-32)];
            else if (k < 44) v = bconj_emb[ibc[e]*4 + (k-40)];
            else if (k < 48) v = bring_emb[ibr[e]*4 + (k-44)];
            else if (k < 52) v = bstereo_emb[ibs[e]*4 + (k-48)];
            else {
                int j = k - 52;
                float dd = de - erdl[e];
                float hr = erdl[e] > 0.f ? 1.f : 0.f;
                v = fabsf(dd)*refW[j] + dd*refW[8+j] + hr*refW[16+j] + refb[j];
            }
            As[e * AP1 + k] = f2bf(v);
        }
    }
    __syncthreads();

    // ---- tiny MFMA GEMM (misc) + fused srcdst gather-add, all in epilogue
    const int wid = tid >> 6, lane = tid & 63;
    const int lr = lane & 15, lkb = (lane >> 4) << 3;
    const int nt0 = wid * 6;                  // 25 tiles / 4 waves, 7 each (overlap dup)
    {
        f32x4 acc[7];
        #pragma unroll
        for (int t = 0; t < 7; ++t) acc[t] = (f32x4){0.f, 0.f, 0.f, 0.f};

        #pragma unroll
        for (int ks = 0; ks < 2; ++ks) {
            int kb = ks * 32 + lkb;
            bf16x8 a0 = *(const bf16x8*)&As[lr * AP1 + kb];
            #pragma unroll
            for (int t = 0; t < 7; ++t) {
                bf16x8 b = *(const bf16x8*)&Wt1[(size_t)((nt0 + t) * 16 + lr) * 64 + kb];
                acc[t] = __builtin_amdgcn_mfma_f32_16x16x32_bf16(a0, b, acc[t], 0, 0, 0);
            }
        }
        const int rbase = (lane >> 4) << 2;
        int se[4], de_[4];
        #pragma unroll
        for (int r = 0; r < 4; ++r) { se[r] = srcl[rbase + r]; de_[r] = dstl[rbase + r]; }
        #pragma unroll
        for (int t = 0; t < 7; ++t) {
            const int col = (nt0 + t) * 16 + lr;
            #pragma unroll
            for (int r = 0; r < 4; ++r) {
                float add = bf2f(srcdst[(size_t)se[r] * 800 + col])
                          + bf2f(srcdst[(size_t)de_[r] * 800 + 400 + col]);
                wl[(rbase + r) * WLP + col] = f2bf(acc[t][r] + add);
            }
        }
    }
    __syncthreads();

    // ---- messages with run-accumulation (edges sorted by dst); all operands in LDS
    {
        int cls = 0, cc = 0, ii = 0, ia = 0, ib = 0, hoff = 0, wB1 = 0, wB2 = 0;
        if (tid < 96)       { cls = 0; cc = tid / 3;        ii = tid % 3;        hoff = 256 + tid; wB1 = 256 + cc; wB2 = 288 + cc; }
        else if (tid < 192) { int j = tid - 96; cls = 1; cc = j / 3; ii = j % 3; hoff = 352 + j;   wB1 = 320 + cc; wB2 = 352 + cc; }
        else                { int j = tid - 192; cls = 2; cc = j / 5;            hoff = 448 + j;   wB1 = 384 + cc; }
        ia = (ii + 1) % 3; ib = (ii + 2) % 3;

        const bool hasC = tid < 16;
        const int jC = 64 + tid;          // l2 channel slot 64..79
        const int hoffC = 448 + jC;       // feature offset 512..527
        const int wC = 384 + jC / 5;

        float accA = 0.f, accB = 0.f, accC = 0.f;
        for (int e = 0; e < ETM; ++e) {
            const unsigned short* hs = &hsl[e * HSP];
            accA = fmaf(bf2f(wl[e * WLP + tid]), bf2f(hs[tid]), accA);
            float m;
            if (cls == 0) {
                float wv1 = bf2f(wl[e * WLP + wB1]), wsv = bf2f(wl[e * WLP + wB2]);
                m = wv1 * bf2f(hs[hoff]) + wsv * svl[e * VDIM + cc] * y1l[e][ii];
            } else if (cls == 1) {
                float wv2 = bf2f(wl[e * WLP + wB1]), wcx = bf2f(wl[e * WLP + wB2]);
                float va = bf2f(hs[256 + cc * 3 + ia]), vb = bf2f(hs[256 + cc * 3 + ib]);
                m = wv2 * bf2f(hs[hoff]) + wcx * (va * y1l[e][ib] - vb * y1l[e][ia]);
            } else {
                m = bf2f(wl[e * WLP + wB1]) * bf2f(hs[hoff]);
            }
            accB += m;
            if (hasC) accC = fmaf(bf2f(wl[e * WLP + wC]), bf2f(hs[hoffC]), accC);

            bool fl = (e == ETM - 1) || (dstl[e + 1] != dstl[e]);
            if (fl) {
                int d = dstl[e];
                atomicAdd(&agg[(size_t)d * FEAT + tid], accA);
                atomicAdd(&agg[(size_t)d * FEAT + 256 + tid], accB);
                if (hasC) atomicAdd(&agg[(size_t)d * FEAT + hoffC], accC);
                accA = 0.f; accB = 0.f; accC = 0.f;
            }
        }
    }
}

// ================================================================ proj kernel: us = silu(agg_s*DEG_INV @ proj_s)
__global__ __launch_bounds__(256) void proj_kernel(
    const float* __restrict__ agg, const unsigned short* __restrict__ Ps,
    float* __restrict__ us_buf)
{
    __shared__ unsigned short As3[32 * AP3];
    const int tid = threadIdx.x;
    const int n0 = blockIdx.x * 32;

    for (int e = 0; e < 32; ++e) {
        int n = n0 + e;
        float v = (n < NN) ? agg[(size_t)n * FEAT + tid] * DEG_INV : 0.f;
        As3[e * AP3 + tid] = f2bf(v);
    }
    __syncthreads();

    const int wid = tid >> 6, lane = tid & 63;
    const int lr = lane & 15, lkb = (lane >> 4) << 3;
    const int rbase = (lane >> 4) << 2;
    const int nt0 = wid * 4;          // 16 tiles over 4 waves

    f32x4 acc[2][4];
    #pragma unroll
    for (int m = 0; m < 2; ++m)
        #pragma unroll
        for (int t = 0; t < 4; ++t) acc[m][t] = (f32x4){0.f, 0.f, 0.f, 0.f};

    for (int ks = 0; ks < 8; ++ks) {
        int kb = ks * 32 + lkb;
        bf16x8 a0 = *(const bf16x8*)&As3[lr * AP3 + kb];
        bf16x8 a1 = *(const bf16x8*)&As3[(16 + lr) * AP3 + kb];
        #pragma unroll
        for (int t = 0; t < 4; ++t) {
            bf16x8 b = *(const bf16x8*)&Ps[(size_t)((nt0 + t) * 16 + lr) * 256 + kb];
            acc[0][t] = __builtin_amdgcn_mfma_f32_16x16x32_bf16(a0, b, acc[0][t], 0, 0, 0);
            acc[1][t] = __builtin_amdgcn_mfma_f32_16x16x32_bf16(a1, b, acc[1][t], 0, 0, 0);
        }
    }
    #pragma unroll
    for (int t = 0; t < 4; ++t) {
        int col = (nt0 + t) * 16 + lr;
        #pragma unroll
        for (int m = 0; m < 2; ++m) {
            #pragma unroll
            for (int r = 0; r < 4; ++r) {
                int n = n0 + m * 16 + rbase + r;
                if (n < NN) {
                    float x = acc[m][t][r];
                    us_buf[(size_t)n * SDIM + col] = x / (1.f + expf(-x));
                }
            }
        }
    }
}

// ================================================================ node kernel
__device__ __forceinline__ float block_reduce_sum(float v, float* red, int tid) {
    #pragma unroll
    for (int off = 32; off > 0; off >>= 1) v += __shfl_down(v, off, 64);
    if ((tid & 63) == 0) red[tid >> 6] = v;
    __syncthreads();
    float s = red[0] + red[1] + red[2] + red[3];
    __syncthreads();
    return s;
}

__global__ __launch_bounds__(256) void node_kernel(
    const float* __restrict__ hcur, const float* __restrict__ ada_buf,
    const float* __restrict__ agg, const float* __restrict__ us_buf,
    const float* __restrict__ proj_v1, const float* __restrict__ proj_v2,
    const float* __restrict__ proj_l2,
    float* __restrict__ hnext, unsigned short* __restrict__ hbnext)
{
    const int n = blockIdx.x;
    const int tid = threadIdx.x;
    __shared__ float ada[ADA];
    __shared__ float av[272];
    __shared__ float vbuf[272];
    __shared__ float red[8];

    for (int i = tid; i < 272; i += 256)
        av[i] = agg[(size_t)n * FEAT + 256 + i] * DEG_INV;
    for (int r = 0; r < 3; ++r) {
        int col = r * 256 + tid;
        if (col < ADA) ada[col] = ada_buf[(size_t)n * ADA + col];
    }
    __syncthreads();

    float sn = hcur[(size_t)n * FEAT + tid] + us_buf[(size_t)n * SDIM + tid];

    if (tid < 96) {
        int d = tid / 3, i = tid - d * 3;
        float a = 0.f;
        #pragma unroll
        for (int c = 0; c < VDIM; ++c) a = fmaf(av[c*3 + i], proj_v1[c * VDIM + d], a);
        vbuf[tid] = hcur[(size_t)n * FEAT + SDIM + tid] + a;
    } else if (tid < 192) {
        int t2 = tid - 96;
        int d = t2 / 3, i = t2 - d * 3;
        float a = 0.f;
        #pragma unroll
        for (int c = 0; c < VDIM; ++c) a = fmaf(av[96 + c*3 + i], proj_v2[c * VDIM + d], a);
        vbuf[tid] = hcur[(size_t)n * FEAT + SDIM + 3*VDIM + t2] + a;
    }
    if (tid < 80) {
        int d = tid / 5, i = tid - d * 5;
        float a = 0.f;
        #pragma unroll
        for (int c = 0; c < L2DIM; ++c) a = fmaf(av[192 + c*5 + i], proj_l2[c * L2DIM + d], a);
        vbuf[192 + tid] = hcur[(size_t)n * FEAT + SDIM + 6*VDIM + tid] + a;
    }
    __syncthreads();

    float ssum = block_reduce_sum(sn, red, tid);
    float ssq  = block_reduce_sum(sn * sn, red, tid);
    float mu = ssum * (1.f / SDIM);
    float var = ssq * (1.f / SDIM) - mu * mu;
    float rstd = rsqrtf(var + 1e-5f);
    {
        float o = (sn - mu) * rstd * (1.f + ada[tid]) + ada[SDIM + tid];
        hnext[(size_t)n * FEAT + tid] = o;
        if (hbnext) hbnext[(size_t)n * FEAT + tid] = f2bf(o);
    }

    float q1 = (tid < 96) ? vbuf[tid] * vbuf[tid] : 0.f;
    float S1 = block_reduce_sum(q1, red, tid);
    float q2 = (tid >= 96 && tid < 192) ? vbuf[tid] * vbuf[tid] : 0.f;
    float S2 = block_reduce_sum(q2, red, tid);
    float q3 = (tid < 80) ? vbuf[192 + tid] * vbuf[192 + tid] : 0.f;
    float S3 = block_reduce_sum(q3, red, tid);

    float r1 = rsqrtf(S1 * (1.f / VDIM) + 1e-5f);
    float r2 = rsqrtf(S2 * (1.f / VDIM) + 1e-5f);
    float r3 = rsqrtf(S3 * (1.f / L2DIM) + 1e-5f);

    if (tid < 96) {
        int d = tid / 3;
        float o = vbuf[tid] * r1 * (1.f + ada[2*SDIM + d]);
        hnext[(size_t)n * FEAT + SDIM + tid] = o;
        if (hbnext) hbnext[(size_t)n * FEAT + SDIM + tid] = f2bf(o);
    } else if (tid < 192) {
        int t2 = tid - 96;
        int d = t2 / 3;
        float o = vbuf[tid] * r2 * (1.f + ada[2*SDIM + VDIM + d]);
        hnext[(size_t)n * FEAT + SDIM + 3*VDIM + t2] = o;
        if (hbnext) hbnext[(size_t)n * FEAT + SDIM + 3*VDIM + t2] = f2bf(o);
    }
    if (tid < 80) {
        int d = tid / 5;
        float o = vbuf[192 + tid] * r3 * (1.f + ada[2*SDIM + 2*VDIM + d]);
        hnext[(size_t)n * FEAT + SDIM + 6*VDIM + tid] = o;
        if (hbnext) hbnext[(size_t)n * FEAT + SDIM + 6*VDIM + tid] = f2bf(o);
    }
}

// ================================================================ launch
extern "C" void kernel_launch(void* const* d_in, const int* in_sizes, int n_in,
                              void* d_out, int out_size, void* d_ws, size_t ws_size,
                              hipStream_t stream) {
    const float* h_in   = (const float*)d_in[0];
    const float* coords = (const float*)d_in[1];
    const float* erd    = (const float*)d_in[2];
    const float* t_emb  = (const float*)d_in[3];
    const float* etype_emb   = (const float*)d_in[4];
    const float* btype_emb   = (const float*)d_in[5];
    const float* bconj_emb   = (const float*)d_in[6];
    const float* bring_emb   = (const float*)d_in[7];
    const float* bstereo_emb = (const float*)d_in[8];
    const float* refW   = (const float*)d_in[9];
    const float* refb   = (const float*)d_in[10];
    const float* edgeW  = (const float*)d_in[11];
    const float* edgeb  = (const float*)d_in[12];
    const float* svW    = (const float*)d_in[13];
    const float* proj_s = (const float*)d_in[14];
    const float* proj_v1= (const float*)d_in[15];
    const float* proj_v2= (const float*)d_in[16];
    const float* proj_l2= (const float*)d_in[17];
    const float* adaW   = (const float*)d_in[18];
    const float* adab   = (const float*)d_in[19];
    const int* eidx     = (const int*)d_in[20];
    const int* etype    = (const int*)d_in[21];
    const int* ebt      = (const int*)d_in[22];
    const int* ebc      = (const int*)d_in[23];
    const int* ebr      = (const int*)d_in[24];
    const int* ebs      = (const int*)d_in[25];

    float* ws_f     = (float*)d_ws;
    float* sv       = ws_f;                           // N*32
    float* agg      = sv + (size_t)NN * VDIM;         // N*528
    float* h1       = agg + (size_t)NN * FEAT;        // N*528
    float* ada_buf  = h1 + (size_t)NN * FEAT;         // N*592
    float* us_buf   = ada_buf + (size_t)NN * ADA;     // N*256
    unsigned short* srcdst = (unsigned short*)(us_buf + (size_t)NN * SDIM);  // N*800
    unsigned short* hb     = srcdst + (size_t)NN * 800;                      // N*528
    unsigned short* Wt1    = hb + (size_t)NN * FEAT;                         // 400*64
    unsigned short* Bn     = Wt1 + (size_t)WOUT * 64;                        // 800*384
    unsigned short* Ba     = Bn + (size_t)800 * 384;                         // 592*128
    unsigned short* Bsv    = Ba + (size_t)ADA * 128;                         // 32*256
    unsigned short* Ps     = Bsv + (size_t)VDIM * 256;                       // 256*256
    int* cnt    = (int*)(Ps + (size_t)SDIM * 256);    // N
    int* cursor = cnt + NN;                           // N
    int* perm   = cursor + NN;                        // E

    // ---- sort edges by dst (once; reused by both layers)
    hipMemsetAsync(cnt, 0, NN * sizeof(int), stream);
    hist_kernel<<<(NE + 255) / 256, 256, 0, stream>>>(eidx, cnt);
    scan_kernel<<<1, 1024, 0, stream>>>(cnt, cursor);
    scatter_kernel<<<(NE + 255) / 256, 256, 0, stream>>>(eidx, cursor, perm);
    hb_kernel<<<(NN * FEAT / 4 + 255) / 256, 256, 0, stream>>>(h_in, hb);

    for (int l = 0; l < 2; ++l) {
        const float* hcur = (l == 0) ? h_in : h1;
        float* hnext      = (l == 0) ? h1 : (float*)d_out;
        const float* W    = edgeW + (size_t)l * 700 * WOUT;

        hipMemsetAsync(agg, 0, (size_t)NN * FEAT * sizeof(float), stream);
        prep_kernel<<<(O5 + 255) / 256, 256, 0, stream>>>(
            W, adaW + (size_t)l * TDIM * ADA, svW + (size_t)l * SDIM * VDIM,
            proj_s + (size_t)l * SDIM * SDIM, Wt1, Bn, Ba, Bsv, Ps);
        nodeproj_kernel<<<(NN + 31) / 32, 256, 0, stream>>>(
            hb, t_emb, Bn, Ba, Bsv, edgeb + l * WOUT, adab + l * ADA,
            srcdst, ada_buf, sv);
        edge_kernel<<<NE / ETM, 256, 0, stream>>>(
            hb, coords, erd, sv, Wt1, srcdst, perm,
            eidx, etype, ebt, ebc, ebr, ebs,
            etype_emb + l * 144, btype_emb + l * 48, bconj_emb + l * 12,
            bring_emb + l * 12, bstereo_emb + l * 20,
            refW + l * 24, refb + l * 8,
            agg);
        proj_kernel<<<(NN + 31) / 32, 256, 0, stream>>>(agg, Ps, us_buf);
        node_kernel<<<NN, 256, 0, stream>>>(
            hcur, ada_buf, agg, us_buf,
            proj_v1 + l * VDIM * VDIM, proj_v2 + l * VDIM * VDIM,
            proj_l2 + l * L2DIM * L2DIM,
            hnext, (l == 0) ? hb : (unsigned short*)nullptr);
    }
}